// Round 3
// baseline (869.535 us; speedup 1.0000x reference)
//
#include <hip/hip_runtime.h>
#include <math.h>

#define NN 100000
#define NE 200000
#define HD 128
#define CAPN 4096
#define CAPB 256
#define NGROUP 21
#define NBLK 192
#define AP 136   // bf16 LDS row pitch (shorts)
#define MP 132   // f32 LDS msg row pitch
#define NTHR 256

typedef short bf16x8 __attribute__((ext_vector_type(8)));
typedef float f32x4 __attribute__((ext_vector_type(4)));

// workspace byte offsets
#define OFF_NCNT   0                // 21 ints
#define OFF_BAR    192              // 2 ints: barrier counter + phase flag
#define OFF_BECNT  256              // 1344 ints (live edges per (group,dst-tile) bucket)
#define OFF_ZCNT   5632             // 21*4096*8 ints (zero-edge counts per dst,src-gate)
#define MEMSET_BYTES 2758144        // covers ncnt+bar+becnt+zcnt
#define OFF_HSTYPE 2758144          // 6*128 f32
#define OFF_HSW1   2761216          // 3*6*128 f32
#define OFF_ZTAB   2770432          // 3*6*128 f32 (msg of a zero-hf src, per gi,src-gate)
#define OFF_WBMLP  2779648          // 3*3*16384 bf16 swizzled B-frags
#define OFF_WBIH   3074560          // 3*49152 bf16 swizzled B-frags
#define OFF_NLIST  3369472          // 21*4096 ints
#define OFF_NSLOT  3713536          // NN ints
#define OFF_EPK    4113536          // 1344*256 ints: src | gate<<17 | localslot<<23

#define SWTOT (3 * 3 * 16384 + 3 * 49152)

__device__ __forceinline__ int gi_of(int g) {
    return (g == 3) ? 0 : (g == 2) ? 1 : (g == 5) ? 2 : -1;
}

__device__ __forceinline__ unsigned short f2bf(float f) {
    unsigned int u = __float_as_uint(f);
    u += 0x7FFF + ((u >> 16) & 1);   // RNE
    return (unsigned short)(u >> 16);
}

// Graph-capture-safe grid barrier. Residency structurally guaranteed:
// 192 blocks <= 256 CUs even at 1 block/CU, so no deadlock possible.
// Counter self-resets (last arrival zeroes it BEFORE releasing the flag);
// flag lives in the memset region so each graph replay restarts at 0.
__device__ __forceinline__ void grid_barrier(int* bar, int phase) {
    __syncthreads();
    if (threadIdx.x == 0) {
        __threadfence();
        int t = __hip_atomic_fetch_add(bar, 1, __ATOMIC_ACQ_REL,
                                       __HIP_MEMORY_SCOPE_AGENT);
        if (t == NBLK - 1) {
            __hip_atomic_store(bar, 0, __ATOMIC_RELAXED, __HIP_MEMORY_SCOPE_AGENT);
            __hip_atomic_store(bar + 1, phase, __ATOMIC_RELEASE,
                               __HIP_MEMORY_SCOPE_AGENT);
        } else {
            while (__hip_atomic_load(bar + 1, __ATOMIC_ACQUIRE,
                                     __HIP_MEMORY_SCOPE_AGENT) < phase)
                __builtin_amdgcn_s_sleep(1);
        }
    }
    __syncthreads();
}

// ---------------------------------------------------------------------------
// prep1: block 0 -> hs_type + hsW1; blocks 1..18 -> ztab rows (self-contained);
// blocks 19+ -> weight swizzle + group_nodes (LDS-aggregated).
// ---------------------------------------------------------------------------
__global__ __launch_bounds__(NTHR) void prep1_kernel(
    const int* __restrict__ gate, const int* __restrict__ lvl,
    const float* __restrict__ Ws, const float* __restrict__ Wt,
    const float* __restrict__ hs_W, const float* __restrict__ hs_b,
    const float* __restrict__ w1, const float* __restrict__ b1,
    const float* __restrict__ w2, const float* __restrict__ b2,
    const float* __restrict__ w3, const float* __restrict__ b3,
    const float* __restrict__ wih,
    float* __restrict__ hs_type, float* __restrict__ hsW1,
    float* __restrict__ ztab,
    unsigned short* __restrict__ wbmlp, unsigned short* __restrict__ wbih,
    int* __restrict__ ncnt, int* __restrict__ nlist, int* __restrict__ nslot) {
    __shared__ float lht[6 * HD];
    __shared__ float s0[HD], s1[HD], s2[HD];
    __shared__ int lcnt[NGROUP], lbase[NGROUP];
    const int bid = blockIdx.x, tid = threadIdx.x;

    if (bid == 0) {
        for (int idx = tid; idx < 6 * HD; idx += NTHR) {
            int t = idx >> 7, c = idx & 127;
            float acc = hs_b[c];
            for (int k = 0; k < HD; k++) acc = fmaf(Ws[t * HD + k], hs_W[k * HD + c], acc);
            for (int k = 0; k < HD; k++) acc = fmaf(Wt[t * HD + k], hs_W[(HD + k) * HD + c], acc);
            lht[idx] = acc;
            hs_type[idx] = acc;
        }
        __syncthreads();
        for (int idx = tid; idx < 3 * 6 * HD; idx += NTHR) {
            int gi = idx / (6 * HD);
            int t = (idx >> 7) % 6;
            int c = idx & 127;
            const float* w = w1 + gi * (2 * HD * HD);  // top half rows 0..127
            float acc = 0.f;
            for (int k = 0; k < HD; k++) acc = fmaf(lht[t * HD + k], w[k * HD + c], acc);
            hsW1[idx] = acc;
        }
    } else if (bid <= 18) {
        // ztab[gi][t] = MLP_gi([hs_type[t], 0]) — fp32, self-contained
        int gi = (bid - 1) / 6, t = (bid - 1) % 6;
        int c = tid;
        if (c < HD) {
            float acc = hs_b[c];
            for (int k = 0; k < HD; k++) acc = fmaf(Ws[t * HD + k], hs_W[k * HD + c], acc);
            for (int k = 0; k < HD; k++) acc = fmaf(Wt[t * HD + k], hs_W[(HD + k) * HD + c], acc);
            s0[c] = acc;
        }
        __syncthreads();
        if (c < HD) {
            const float* w = w1 + gi * (2 * HD * HD);  // top half
            float acc = b1[gi * HD + c];
            for (int k = 0; k < HD; k++) acc = fmaf(s0[k], w[k * HD + c], acc);
            s1[c] = fmaxf(acc, 0.f);
        }
        __syncthreads();
        if (c < HD) {
            const float* w = w2 + gi * (HD * HD);
            float acc = b2[gi * HD + c];
            for (int k = 0; k < HD; k++) acc = fmaf(s1[k], w[k * HD + c], acc);
            s2[c] = fmaxf(acc, 0.f);
        }
        __syncthreads();
        if (c < HD) {
            const float* w = w3 + gi * (HD * HD);
            float acc = b3[gi * HD + c];
            for (int k = 0; k < HD; k++) acc = fmaf(s2[k], w[k * HD + c], acc);
            ztab[(gi * 6 + t) * HD + c] = acc;
        }
    } else {
        const int nb = gridDim.x - 19;          // worker blocks
        const int wb = bid - 19;
        // weight swizzle into MFMA B-fragment layout
        for (int id = wb * NTHR + tid; id < SWTOT; id += nb * NTHR) {
            if (id < 3 * 3 * 16384) {
                int gi = id / 49152;
                int rem = id % 49152;
                int layer = rem / 16384;
                int e = rem % 16384;
                int k = e >> 7, n = e & 127;
                float v;
                if (layer == 0)      v = w1[gi * (2 * HD * HD) + (HD + k) * HD + n];
                else if (layer == 1) v = w2[gi * (HD * HD) + k * HD + n];
                else                 v = w3[gi * (HD * HD) + k * HD + n];
                int nt = n >> 4, kc = k >> 5, kq = (k >> 3) & 3, j = k & 7;
                int L = (kq << 4) | (n & 15);
                wbmlp[(size_t)(gi * 3 + layer) * 16384 + ((nt * 4 + kc) * 64 + L) * 8 + j] = f2bf(v);
            } else {
                int id2 = id - 3 * 3 * 16384;
                int gi = id2 / 49152;
                int e = id2 % 49152;
                int k = e / 384, n = e % 384;             // B[k][n] = wih[n][k]
                float v = wih[gi * (384 * HD) + n * HD + k];
                int nt = n >> 4, kc = k >> 5, kq = (k >> 3) & 3, j = k & 7;
                int L = (kq << 4) | (n & 15);
                wbih[(size_t)gi * 49152 + ((nt * 4 + kc) * 64 + L) * 8 + j] = f2bf(v);
            }
        }
        // group_nodes (LDS-aggregated)
        for (int base = wb * NTHR; base < NN; base += nb * NTHR) {
            if (tid < NGROUP) lcnt[tid] = 0;
            __syncthreads();
            int i = base + tid;
            int glob = -1, local = 0;
            if (i < NN) {
                int gi = gi_of(gate[i]);
                int l = lvl[i];
                if (gi >= 0 && l >= 1) {
                    glob = (l - 1) * 3 + gi;
                    local = atomicAdd(&lcnt[glob], 1);
                }
            }
            __syncthreads();
            if (tid < NGROUP) {
                int cc = lcnt[tid];
                lbase[tid] = cc ? atomicAdd(&ncnt[tid], cc) : 0;
            }
            __syncthreads();
            if (glob >= 0) {
                int slot = lbase[glob] + local;
                if (slot < CAPN) {
                    nlist[glob * CAPN + slot] = i;
                    nslot[i] = slot;
                }
            }
            __syncthreads();
        }
    }
}

// ---------------------------------------------------------------------------
// prep2: scatter hs / zero hf + classify edges.
// Live edges -> per-(group, dst-tile) bucket, packed src|gate|localslot.
// Zero-hf edges -> one int atomicAdd into zcnt[(glob,dslot,src_gate)].
// ---------------------------------------------------------------------------
__global__ __launch_bounds__(NTHR) void prep2_kernel(
    const int* __restrict__ gate, const int* __restrict__ lvl,
    const int* __restrict__ ei, const int* __restrict__ nslot,
    const float* __restrict__ hs_type, float* __restrict__ out,
    int* __restrict__ becnt, int* __restrict__ epk,
    int* __restrict__ zcnt) {
    const int stride = gridDim.x * NTHR;
    const int tid0 = blockIdx.x * NTHR + threadIdx.x;

    const float4* ht4 = (const float4*)hs_type;
    float4* o4 = (float4*)out;
    for (int idx = tid0; idx < NN * 32; idx += stride) {
        int i = idx >> 5, q = idx & 31;
        o4[idx] = ht4[gate[i] * 32 + q];
        o4[(size_t)NN * 32 + idx] = make_float4(0.f, 0.f, 0.f, 0.f);
    }

    for (int e = tid0; e < NE; e += stride) {
        int d = ei[NE + e];
        int gd = gi_of(gate[d]);
        int ld = lvl[d];
        if (gd < 0 || ld < 1) continue;
        int g = (ld - 1) * 3 + gd;
        int s = ei[e];
        int dsl = nslot[d];
        int gs = gate[s], ls = lvl[s];
        bool live = (gi_of(gs) >= 0) && (ls >= 1) && (ls < ld);
        if (live) {
            int bucket = g * 64 + (dsl >> 6);
            int slot = atomicAdd(&becnt[bucket], 1);
            if (slot < CAPB)
                epk[(size_t)bucket * CAPB + slot] = s | (gs << 17) | ((dsl & 63) << 23);
        } else {
            atomicAdd(&zcnt[((size_t)g * CAPN + dsl) * 8 + gs], 1);
        }
    }
}

// ---------------------------------------------------------------------------
// levels_kernel: ALL 7 levels in one persistent kernel with a manual
// software grid barrier (graph-capture-safe; 192 blocks always co-resident).
// Block (gi,tilei) owns dst slots [tile,tile+64) of group gi at every level.
// ztab fold for the NEXT level is computed before the barrier (independent
// of hf), keeping the inter-barrier critical path at gather->MFMA->store.
// ---------------------------------------------------------------------------
__global__ __launch_bounds__(NTHR) void levels_kernel(
    const int* ncnt, const int* nlist, const int* becnt, const int* epk,
    const int* zcnt, const float* ztab, const float* hsW1,
    const unsigned short* wbmlp, const unsigned short* wbih,
    const float* b1, const float* b2, const float* b3,
    const float* bih, const float* bhh, int* bar, float* out) {
    __shared__ unsigned short A[64 * AP];   // 17408 B
    __shared__ float msgf[64 * MP];         // 33792 B
    __shared__ float hsw[6 * 132];          // 3168 B
    __shared__ int zs[64 * 8];              // 2048 B
    __shared__ int nls[7 * 64];             // 1792 B
    __shared__ int ncs[24];
    __shared__ int ecs[8];

    const int gi = blockIdx.x >> 6;
    const int tilei = blockIdx.x & 63;
    const int tile = tilei * 64;
    const int tid = threadIdx.x;
    const int ln = tid & 63, wv = tid >> 6;
    const int lc = ln & 15, quad = ln >> 4;
    const int rbase = wv * 16;

    // ---- prologue: stage all per-block metadata once ----
    if (tid < NGROUP) ncs[tid] = ncnt[tid];
    if (tid >= 32 && tid < 39) ecs[tid - 32] = becnt[((tid - 32) * 3 + gi) * 64 + tilei];
    for (int i = tid; i < 7 * 64; i += NTHR)
        nls[i] = nlist[((i >> 6) * 3 + gi) * CAPN + tile + (i & 63)];
    for (int i = tid; i < 6 * 132; i += NTHR) {
        int t = i / 132, c = i % 132;
        hsw[i] = (c < HD) ? hsW1[(gi * 6 + t) * HD + c] : 0.f;
    }
    for (int i = tid; i < 512; i += NTHR)                       // level-1 zcnt (glob = gi)
        zs[i] = zcnt[((size_t)(gi * CAPN + tile)) * 8 + i];

    float b1v[8], b2v[8], b3v[8];
    float biR[8], bhR[8], biZ[8], bhZ[8], biN[8], bhN[8];
#pragma unroll
    for (int nt = 0; nt < 8; nt++) {
        int c = nt * 16 + lc;
        b1v[nt] = b1[gi * HD + c];
        b2v[nt] = b2[gi * HD + c];
        b3v[nt] = b3[gi * HD + c];
        biR[nt] = bih[gi * 384 + c];        bhR[nt] = bhh[gi * 384 + c];
        biZ[nt] = bih[gi * 384 + 128 + c];  bhZ[nt] = bhh[gi * 384 + 128 + c];
        biN[nt] = bih[gi * 384 + 256 + c];  bhN[nt] = bhh[gi * 384 + 256 + c];
    }
    __syncthreads();

    const f32x4* zt4 = (const f32x4*)ztab;
    const unsigned short* WB = wbmlp + (size_t)gi * 3 * 16384;
    const unsigned short* WG = wbih + (size_t)gi * 49152;
    float* hfbuf = out + (size_t)NN * HD;

    // ---- fold level 1 msg accumulator from staged zcnt ----
    {
        int cnt1 = ncs[gi] > CAPN ? CAPN : ncs[gi];
        if (tile < cnt1) {
            for (int id = tid; id < 64 * 32; id += NTHR) {
                int row = id >> 5, lane = id & 31;
                f32x4 acc = {0.f, 0.f, 0.f, 0.f};
#pragma unroll
                for (int t = 0; t < 6; t++) {
                    int ct = zs[row * 8 + t];
                    if (ct) {
                        float f = (float)ct;
                        f32x4 z = zt4[(gi * 6 + t) * 32 + lane];
                        acc.x = fmaf(f, z.x, acc.x);
                        acc.y = fmaf(f, z.y, acc.y);
                        acc.z = fmaf(f, z.z, acc.z);
                        acc.w = fmaf(f, z.w, acc.w);
                    }
                }
                *(f32x4*)&msgf[row * MP + lane * 4] = acc;
            }
        }
    }

    for (int l = 1; l <= 7; ++l) {
        const int glob = (l - 1) * 3 + gi;
        int cnt0 = ncs[glob]; if (cnt0 > CAPN) cnt0 = CAPN;
        const bool active = (tile < cnt0);
        if (active) {
            const int nv = min(64, cnt0 - tile);
            int ecb = ecs[l - 1]; if (ecb > CAPB) ecb = CAPB;
            if (ecb) {
                const int* ep = epk + (size_t)(glob * 64 + tilei) * CAPB;
                for (int c0 = 0; c0 < ecb; c0 += 64) {
                    int ne = min(64, ecb - c0);
                    // wave-local staging of hf[src] (bf16)
                    {
                        int row = rbase + (ln >> 2), q = ln & 3;
                        unsigned int* Au = (unsigned int*)A;
                        int base = (row * AP + q * 32) >> 1;
                        if (row < ne) {
                            int s = ep[c0 + row] & 0x1FFFF;
                            const float4* src4 = (const float4*)(hfbuf + (size_t)s * HD + q * 32);
#pragma unroll
                            for (int i = 0; i < 8; i++) {
                                float4 v = src4[i];
                                Au[base + i * 2]     = f2bf(v.x) | ((unsigned int)f2bf(v.y) << 16);
                                Au[base + i * 2 + 1] = f2bf(v.z) | ((unsigned int)f2bf(v.w) << 16);
                            }
                        } else {
#pragma unroll
                            for (int i = 0; i < 16; i++) Au[base + i] = 0u;
                        }
                    }
                    int sg = 0, lo = 0;
                    if (ln < 16) {
                        int r2 = rbase + ln;
                        if (r2 < ne) {
                            int p = ep[c0 + r2];
                            sg = (p >> 17) & 7;
                            lo = (p >> 23) & 63;
                        }
                    }

                    // layer 1: relu(hsW1[gate_src] + hf@W1bot + b1), in-place
                    {
                        bf16x8 af[4];
#pragma unroll
                        for (int kc = 0; kc < 4; kc++)
                            af[kc] = *(bf16x8*)&A[(rbase + lc) * AP + kc * 32 + quad * 8];
                        for (int nt = 0; nt < 8; nt++) {
                            f32x4 acc = {0.f, 0.f, 0.f, 0.f};
#pragma unroll
                            for (int kc = 0; kc < 4; kc++) {
                                bf16x8 bf = *(const bf16x8*)&WB[((nt * 4 + kc) * 64 + ln) * 8];
                                acc = __builtin_amdgcn_mfma_f32_16x16x32_bf16(af[kc], bf, acc, 0, 0, 0);
                            }
#pragma unroll
                            for (int r = 0; r < 4; r++) {
                                int row = rbase + quad * 4 + r;
                                int sgr = __shfl(sg, quad * 4 + r);
                                float v = acc[r] + hsw[sgr * 132 + nt * 16 + lc] + b1v[nt];
                                A[row * AP + nt * 16 + lc] = f2bf(fmaxf(v, 0.f));
                            }
                        }
                    }
                    // layer 2
                    {
                        bf16x8 af[4];
#pragma unroll
                        for (int kc = 0; kc < 4; kc++)
                            af[kc] = *(bf16x8*)&A[(rbase + lc) * AP + kc * 32 + quad * 8];
                        for (int nt = 0; nt < 8; nt++) {
                            f32x4 acc = {0.f, 0.f, 0.f, 0.f};
#pragma unroll
                            for (int kc = 0; kc < 4; kc++) {
                                bf16x8 bf = *(const bf16x8*)&WB[16384 + ((nt * 4 + kc) * 64 + ln) * 8];
                                acc = __builtin_amdgcn_mfma_f32_16x16x32_bf16(af[kc], bf, acc, 0, 0, 0);
                            }
#pragma unroll
                            for (int r = 0; r < 4; r++) {
                                int row = rbase + quad * 4 + r;
                                A[row * AP + nt * 16 + lc] = f2bf(fmaxf(acc[r] + b2v[nt], 0.f));
                            }
                        }
                    }
                    // layer 3 + LDS scatter-add into msgf
                    {
                        bf16x8 af[4];
#pragma unroll
                        for (int kc = 0; kc < 4; kc++)
                            af[kc] = *(bf16x8*)&A[(rbase + lc) * AP + kc * 32 + quad * 8];
                        for (int nt = 0; nt < 8; nt++) {
                            f32x4 acc = {0.f, 0.f, 0.f, 0.f};
#pragma unroll
                            for (int kc = 0; kc < 4; kc++) {
                                bf16x8 bf = *(const bf16x8*)&WB[2 * 16384 + ((nt * 4 + kc) * 64 + ln) * 8];
                                acc = __builtin_amdgcn_mfma_f32_16x16x32_bf16(af[kc], bf, acc, 0, 0, 0);
                            }
#pragma unroll
                            for (int r = 0; r < 4; r++) {
                                int row = rbase + quad * 4 + r;
                                if (row < ne) {
                                    int lr = __shfl(lo, quad * 4 + r);
                                    atomicAdd(&msgf[lr * MP + nt * 16 + lc], acc[r] + b3v[nt]);
                                }
                            }
                        }
                    }
                }
            }
            __syncthreads();   // edge atomics visible before GRU reads msgf

            // ---- GRU: gin = msg @ wih.T + bih ; gh = bhh (h_old == 0) ----
            int nd = -1;
            if (ln < 16) {
                int r2 = rbase + ln;
                nd = (r2 < nv) ? nls[(l - 1) * 64 + r2] : -1;
            }
            bf16x8 af[4];
#pragma unroll
            for (int kc = 0; kc < 4; kc++) {
                const float* mp = &msgf[(rbase + lc) * MP + kc * 32 + quad * 8];
                f32x4 v0 = *(const f32x4*)mp;
                f32x4 v1 = *(const f32x4*)(mp + 4);
                bf16x8 a;
                a[0] = (short)f2bf(v0.x); a[1] = (short)f2bf(v0.y);
                a[2] = (short)f2bf(v0.z); a[3] = (short)f2bf(v0.w);
                a[4] = (short)f2bf(v1.x); a[5] = (short)f2bf(v1.y);
                a[6] = (short)f2bf(v1.z); a[7] = (short)f2bf(v1.w);
                af[kc] = a;
            }
            for (int nt = 0; nt < 8; nt++) {
                f32x4 aR = {0.f, 0.f, 0.f, 0.f};
                f32x4 aZ = {0.f, 0.f, 0.f, 0.f};
                f32x4 aN = {0.f, 0.f, 0.f, 0.f};
#pragma unroll
                for (int kc = 0; kc < 4; kc++) {
                    bf16x8 bR = *(const bf16x8*)&WG[(((nt)      * 4 + kc) * 64 + ln) * 8];
                    bf16x8 bZ = *(const bf16x8*)&WG[(((nt + 8)  * 4 + kc) * 64 + ln) * 8];
                    bf16x8 bN = *(const bf16x8*)&WG[(((nt + 16) * 4 + kc) * 64 + ln) * 8];
                    aR = __builtin_amdgcn_mfma_f32_16x16x32_bf16(af[kc], bR, aR, 0, 0, 0);
                    aZ = __builtin_amdgcn_mfma_f32_16x16x32_bf16(af[kc], bZ, aZ, 0, 0, 0);
                    aN = __builtin_amdgcn_mfma_f32_16x16x32_bf16(af[kc], bN, aN, 0, 0, 0);
                }
                int c = nt * 16 + lc;
#pragma unroll
                for (int r = 0; r < 4; r++) {
                    int row = rbase + quad * 4 + r;
                    int n = __shfl(nd, quad * 4 + r);
                    if (n >= 0 && row < nv) {
                        float ir = aR[r] + biR[nt] + bhR[nt];
                        float iz = aZ[r] + biZ[nt] + bhZ[nt];
                        float inn = aN[r] + biN[nt];
                        float rg = 1.f / (1.f + expf(-ir));
                        float zg = 1.f / (1.f + expf(-iz));
                        float nst = tanhf(inn + rg * bhN[nt]);
                        hfbuf[(size_t)n * HD + c] = (1.f - zg) * nst;
                    }
                }
            }
        }

        if (l < 7) {
            __syncthreads();                 // all waves done reading msgf / zs
            // fold msg accumulator for level l+1 (independent of hf)
            const int globn = l * 3 + gi;
            for (int i = tid; i < 512; i += NTHR)
                zs[i] = zcnt[((size_t)(globn * CAPN + tile)) * 8 + i];
            __syncthreads();
            int cntn = ncs[globn]; if (cntn > CAPN) cntn = CAPN;
            if (tile < cntn) {
                for (int id = tid; id < 64 * 32; id += NTHR) {
                    int row = id >> 5, lane = id & 31;
                    f32x4 acc = {0.f, 0.f, 0.f, 0.f};
#pragma unroll
                    for (int t = 0; t < 6; t++) {
                        int ct = zs[row * 8 + t];
                        if (ct) {
                            float f = (float)ct;
                            f32x4 z = zt4[(gi * 6 + t) * 32 + lane];
                            acc.x = fmaf(f, z.x, acc.x);
                            acc.y = fmaf(f, z.y, acc.y);
                            acc.z = fmaf(f, z.z, acc.z);
                            acc.w = fmaf(f, z.w, acc.w);
                        }
                    }
                    *(f32x4*)&msgf[row * MP + lane * 4] = acc;
                }
            }
            grid_barrier(bar, l);            // hf stores visible; next level may gather
        }
    }
}

extern "C" void kernel_launch(void* const* d_in, const int* in_sizes, int n_in,
                              void* d_out, int out_size, void* d_ws, size_t ws_size,
                              hipStream_t stream) {
    const int* gate = (const int*)d_in[0];
    const int* lvl  = (const int*)d_in[1];
    const int* ei   = (const int*)d_in[2];
    const float* Ws   = (const float*)d_in[3];
    const float* Wt   = (const float*)d_in[4];
    const float* hs_W = (const float*)d_in[5];
    const float* hs_b = (const float*)d_in[6];
    const float* w1 = (const float*)d_in[7];
    const float* b1 = (const float*)d_in[8];
    const float* w2 = (const float*)d_in[9];
    const float* b2 = (const float*)d_in[10];
    const float* w3 = (const float*)d_in[11];
    const float* b3 = (const float*)d_in[12];
    const float* wih = (const float*)d_in[13];
    // d_in[14] = gru_whh: unused (h_old provably zero for every updated node)
    const float* bih = (const float*)d_in[15];
    const float* bhh = (const float*)d_in[16];
    float* out = (float*)d_out;
    char* ws = (char*)d_ws;

    int*   ncnt    = (int*)(ws + OFF_NCNT);
    int*   bar     = (int*)(ws + OFF_BAR);
    int*   becnt   = (int*)(ws + OFF_BECNT);
    int*   zcnt    = (int*)(ws + OFF_ZCNT);
    float* hs_type = (float*)(ws + OFF_HSTYPE);
    float* hsW1    = (float*)(ws + OFF_HSW1);
    float* ztab    = (float*)(ws + OFF_ZTAB);
    unsigned short* wbmlp = (unsigned short*)(ws + OFF_WBMLP);
    unsigned short* wbih  = (unsigned short*)(ws + OFF_WBIH);
    int*   nlist   = (int*)(ws + OFF_NLIST);
    int*   nslot   = (int*)(ws + OFF_NSLOT);
    int*   epk     = (int*)(ws + OFF_EPK);

    hipMemsetAsync(ws, 0, MEMSET_BYTES, stream);

    prep1_kernel<<<256, NTHR, 0, stream>>>(gate, lvl, Ws, Wt, hs_W, hs_b,
                                           w1, b1, w2, b2, w3, b3, wih,
                                           hs_type, hsW1, ztab, wbmlp, wbih,
                                           ncnt, nlist, nslot);
    prep2_kernel<<<1024, NTHR, 0, stream>>>(gate, lvl, ei, nslot, hs_type, out,
                                            becnt, epk, zcnt);

    levels_kernel<<<NBLK, NTHR, 0, stream>>>(ncnt, nlist, becnt, epk, zcnt,
                                             ztab, hsW1, wbmlp, wbih,
                                             b1, b2, b3, bih, bhh, bar, out);
}

// Round 4
// 505.057 us; speedup vs baseline: 1.7217x; 1.7217x over previous
//
#include <hip/hip_runtime.h>
#include <math.h>

#define NN 100000
#define NE 200000
#define HD 128
#define CAPN 4096
#define CAPB 256
#define NGROUP 21
#define NBLK 192
#define BSTRIDE 32   // barrier slot stride in ints (128 B)
#define AP 136   // bf16 LDS row pitch (shorts)
#define MP 132   // f32 LDS msg row pitch
#define NTHR 256

typedef short bf16x8 __attribute__((ext_vector_type(8)));
typedef float f32x4 __attribute__((ext_vector_type(4)));

// workspace byte offsets
#define OFF_NCNT   0                // 21 ints (pad to 128)
#define OFF_ARR    128              // 192*32 ints: arrive slots (128B apart)
#define OFF_REL    24704            // 192*32 ints: release slots
#define OFF_BECNT  49280            // 1344 ints (live edges per (group,dst-tile) bucket)
#define OFF_ZCNT   54656            // 21*4096*8 ints (zero-edge counts per dst,src-gate)
#define MEMSET_BYTES 2807168        // covers ncnt+arr+rel+becnt+zcnt
#define OFF_HSTYPE 2807168          // 6*128 f32
#define OFF_HSW1   2810240          // 3*6*128 f32
#define OFF_ZTAB   2819456          // 3*6*128 f32 (msg of a zero-hf src, per gi,src-gate)
#define OFF_WBMLP  2828672          // 3*3*16384 bf16 swizzled B-frags
#define OFF_WBIH   3123584          // 3*49152 bf16 swizzled B-frags
#define OFF_NLIST  3418496          // 21*4096 ints
#define OFF_NSLOT  3762560          // NN ints
#define OFF_EPK    4162560          // 1344*256 ints: src | gate<<17 | localslot<<23

#define SWTOT (3 * 3 * 16384 + 3 * 49152)

__device__ __forceinline__ int gi_of(int g) {
    return (g == 3) ? 0 : (g == 2) ? 1 : (g == 5) ? 2 : -1;
}

__device__ __forceinline__ unsigned short f2bf(float f) {
    unsigned int u = __float_as_uint(f);
    u += 0x7FFF + ((u >> 16) & 1);   // RNE
    return (unsigned short)(u >> 16);
}

// Distributed grid barrier (graph-capture-safe; 192 blocks <= 256 CUs so all
// blocks are always resident -> no deadlock). Arrive: each block RELEASE-
// stores its own 128B-strided slot (one wbl2, flushes its XCD L2 to the
// coherent point). Master block polls 191 DISTINCT lines with RELAXED loads
// (no per-poll cache-inv, no same-line queueing -- the round-3 failure mode),
// then RELEASE-stores per-block release slots. Workers poll only their own
// slot. One agent-acquire fence at exit drops stale clean lines (needed for
// hf rows zero-filled in phase 0 and rewritten by other XCDs later).
__device__ __forceinline__ void grid_barrier(int* arr, int* rel, int phase) {
    __syncthreads();   // all block stores drained (vmcnt 0) before arrival
    const int tid = threadIdx.x;
    const int bid = blockIdx.x;
    if (bid == 0) {
        if (tid >= 1 && tid < NBLK) {
            while (__hip_atomic_load(&arr[tid * BSTRIDE], __ATOMIC_RELAXED,
                                     __HIP_MEMORY_SCOPE_AGENT) < phase)
                __builtin_amdgcn_s_sleep(2);
        }
        __syncthreads();                     // all arrivals observed
        if (tid >= 1 && tid < NBLK)
            __hip_atomic_store(&rel[tid * BSTRIDE], phase, __ATOMIC_RELEASE,
                               __HIP_MEMORY_SCOPE_AGENT);
    } else {
        if (tid == 0) {
            __hip_atomic_store(&arr[bid * BSTRIDE], phase, __ATOMIC_RELEASE,
                               __HIP_MEMORY_SCOPE_AGENT);
            while (__hip_atomic_load(&rel[bid * BSTRIDE], __ATOMIC_RELAXED,
                                     __HIP_MEMORY_SCOPE_AGENT) < phase)
                __builtin_amdgcn_s_sleep(2);
        }
    }
    __builtin_amdgcn_fence(__ATOMIC_ACQUIRE, "agent");
    __syncthreads();
}

// ---------------------------------------------------------------------------
// prep1: block 0 -> hs_type + hsW1; blocks 1..18 -> ztab rows (self-contained);
// blocks 19+ -> weight swizzle + group_nodes (LDS-aggregated).
// ---------------------------------------------------------------------------
__global__ __launch_bounds__(NTHR) void prep1_kernel(
    const int* __restrict__ gate, const int* __restrict__ lvl,
    const float* __restrict__ Ws, const float* __restrict__ Wt,
    const float* __restrict__ hs_W, const float* __restrict__ hs_b,
    const float* __restrict__ w1, const float* __restrict__ b1,
    const float* __restrict__ w2, const float* __restrict__ b2,
    const float* __restrict__ w3, const float* __restrict__ b3,
    const float* __restrict__ wih,
    float* __restrict__ hs_type, float* __restrict__ hsW1,
    float* __restrict__ ztab,
    unsigned short* __restrict__ wbmlp, unsigned short* __restrict__ wbih,
    int* __restrict__ ncnt, int* __restrict__ nlist, int* __restrict__ nslot) {
    __shared__ float lht[6 * HD];
    __shared__ float s0[HD], s1[HD], s2[HD];
    __shared__ int lcnt[NGROUP], lbase[NGROUP];
    const int bid = blockIdx.x, tid = threadIdx.x;

    if (bid == 0) {
        for (int idx = tid; idx < 6 * HD; idx += NTHR) {
            int t = idx >> 7, c = idx & 127;
            float acc = hs_b[c];
            for (int k = 0; k < HD; k++) acc = fmaf(Ws[t * HD + k], hs_W[k * HD + c], acc);
            for (int k = 0; k < HD; k++) acc = fmaf(Wt[t * HD + k], hs_W[(HD + k) * HD + c], acc);
            lht[idx] = acc;
            hs_type[idx] = acc;
        }
        __syncthreads();
        for (int idx = tid; idx < 3 * 6 * HD; idx += NTHR) {
            int gi = idx / (6 * HD);
            int t = (idx >> 7) % 6;
            int c = idx & 127;
            const float* w = w1 + gi * (2 * HD * HD);  // top half rows 0..127
            float acc = 0.f;
            for (int k = 0; k < HD; k++) acc = fmaf(lht[t * HD + k], w[k * HD + c], acc);
            hsW1[idx] = acc;
        }
    } else if (bid <= 18) {
        // ztab[gi][t] = MLP_gi([hs_type[t], 0]) — fp32, self-contained
        int gi = (bid - 1) / 6, t = (bid - 1) % 6;
        int c = tid;
        if (c < HD) {
            float acc = hs_b[c];
            for (int k = 0; k < HD; k++) acc = fmaf(Ws[t * HD + k], hs_W[k * HD + c], acc);
            for (int k = 0; k < HD; k++) acc = fmaf(Wt[t * HD + k], hs_W[(HD + k) * HD + c], acc);
            s0[c] = acc;
        }
        __syncthreads();
        if (c < HD) {
            const float* w = w1 + gi * (2 * HD * HD);  // top half
            float acc = b1[gi * HD + c];
            for (int k = 0; k < HD; k++) acc = fmaf(s0[k], w[k * HD + c], acc);
            s1[c] = fmaxf(acc, 0.f);
        }
        __syncthreads();
        if (c < HD) {
            const float* w = w2 + gi * (HD * HD);
            float acc = b2[gi * HD + c];
            for (int k = 0; k < HD; k++) acc = fmaf(s1[k], w[k * HD + c], acc);
            s2[c] = fmaxf(acc, 0.f);
        }
        __syncthreads();
        if (c < HD) {
            const float* w = w3 + gi * (HD * HD);
            float acc = b3[gi * HD + c];
            for (int k = 0; k < HD; k++) acc = fmaf(s2[k], w[k * HD + c], acc);
            ztab[(gi * 6 + t) * HD + c] = acc;
        }
    } else {
        const int nb = gridDim.x - 19;          // worker blocks
        const int wb = bid - 19;
        // weight swizzle into MFMA B-fragment layout
        for (int id = wb * NTHR + tid; id < SWTOT; id += nb * NTHR) {
            if (id < 3 * 3 * 16384) {
                int gi = id / 49152;
                int rem = id % 49152;
                int layer = rem / 16384;
                int e = rem % 16384;
                int k = e >> 7, n = e & 127;
                float v;
                if (layer == 0)      v = w1[gi * (2 * HD * HD) + (HD + k) * HD + n];
                else if (layer == 1) v = w2[gi * (HD * HD) + k * HD + n];
                else                 v = w3[gi * (HD * HD) + k * HD + n];
                int nt = n >> 4, kc = k >> 5, kq = (k >> 3) & 3, j = k & 7;
                int L = (kq << 4) | (n & 15);
                wbmlp[(size_t)(gi * 3 + layer) * 16384 + ((nt * 4 + kc) * 64 + L) * 8 + j] = f2bf(v);
            } else {
                int id2 = id - 3 * 3 * 16384;
                int gi = id2 / 49152;
                int e = id2 % 49152;
                int k = e / 384, n = e % 384;             // B[k][n] = wih[n][k]
                float v = wih[gi * (384 * HD) + n * HD + k];
                int nt = n >> 4, kc = k >> 5, kq = (k >> 3) & 3, j = k & 7;
                int L = (kq << 4) | (n & 15);
                wbih[(size_t)gi * 49152 + ((nt * 4 + kc) * 64 + L) * 8 + j] = f2bf(v);
            }
        }
        // group_nodes (LDS-aggregated)
        for (int base = wb * NTHR; base < NN; base += nb * NTHR) {
            if (tid < NGROUP) lcnt[tid] = 0;
            __syncthreads();
            int i = base + tid;
            int glob = -1, local = 0;
            if (i < NN) {
                int gi = gi_of(gate[i]);
                int l = lvl[i];
                if (gi >= 0 && l >= 1) {
                    glob = (l - 1) * 3 + gi;
                    local = atomicAdd(&lcnt[glob], 1);
                }
            }
            __syncthreads();
            if (tid < NGROUP) {
                int cc = lcnt[tid];
                lbase[tid] = cc ? atomicAdd(&ncnt[tid], cc) : 0;
            }
            __syncthreads();
            if (glob >= 0) {
                int slot = lbase[glob] + local;
                if (slot < CAPN) {
                    nlist[glob * CAPN + slot] = i;
                    nslot[i] = slot;
                }
            }
            __syncthreads();
        }
    }
}

// ---------------------------------------------------------------------------
// levels_kernel: persistent. Phase 0 = old prep2 (hs scatter / hf zero / edge
// classify into buckets+zcnt), then distributed grid barrier, then 7 levels
// with a barrier between consecutive levels. Block (gi,tilei) owns dst slots
// [tile,tile+64) of group gi at every level. ztab fold for the NEXT level is
// computed before the barrier (independent of hf).
// ---------------------------------------------------------------------------
__global__ __launch_bounds__(NTHR) void levels_kernel(
    const int* gate, const int* lvl, const int* ei, const int* nslot,
    const float* hs_type,
    const int* ncnt, const int* nlist, int* becnt, int* epk, int* zcnt,
    const float* ztab, const float* hsW1,
    const unsigned short* wbmlp, const unsigned short* wbih,
    const float* b1, const float* b2, const float* b3,
    const float* bih, const float* bhh,
    int* arr, int* rel, float* out) {
    __shared__ unsigned short A[64 * AP];   // 17408 B
    __shared__ float msgf[64 * MP];         // 33792 B
    __shared__ float hsw[6 * 132];          // 3168 B
    __shared__ int zs[64 * 8];              // 2048 B
    __shared__ int nls[7 * 64];             // 1792 B
    __shared__ int ncs[24];
    __shared__ int ecs[8];

    const int gi = blockIdx.x >> 6;
    const int tilei = blockIdx.x & 63;
    const int tile = tilei * 64;
    const int tid = threadIdx.x;
    const int ln = tid & 63, wv = tid >> 6;
    const int lc = ln & 15, quad = ln >> 4;
    const int rbase = wv * 16;

    // ---- phase 0: hs scatter / hf zero + edge classification (old prep2) ----
    {
        const int stride = NBLK * NTHR;
        const int tid0 = blockIdx.x * NTHR + tid;
        const float4* ht4 = (const float4*)hs_type;
        float4* o4 = (float4*)out;
        for (int idx = tid0; idx < NN * 32; idx += stride) {
            int i = idx >> 5, q = idx & 31;
            o4[idx] = ht4[gate[i] * 32 + q];
            o4[(size_t)NN * 32 + idx] = make_float4(0.f, 0.f, 0.f, 0.f);
        }
        for (int e = tid0; e < NE; e += stride) {
            int d = ei[NE + e];
            int gd = gi_of(gate[d]);
            int ld = lvl[d];
            if (gd < 0 || ld < 1) continue;
            int g = (ld - 1) * 3 + gd;
            int s = ei[e];
            int dsl = nslot[d];
            int gs = gate[s], ls = lvl[s];
            bool live = (gi_of(gs) >= 0) && (ls >= 1) && (ls < ld);
            if (live) {
                int bucket = g * 64 + (dsl >> 6);
                int slot = atomicAdd(&becnt[bucket], 1);
                if (slot < CAPB)
                    epk[(size_t)bucket * CAPB + slot] = s | (gs << 17) | ((dsl & 63) << 23);
            } else {
                atomicAdd(&zcnt[((size_t)g * CAPN + dsl) * 8 + gs], 1);
            }
        }
    }

    // ---- stage prep1-produced metadata (valid since before kernel start) ----
    if (tid < NGROUP) ncs[tid] = ncnt[tid];
    for (int i = tid; i < 7 * 64; i += NTHR)
        nls[i] = nlist[((i >> 6) * 3 + gi) * CAPN + tile + (i & 63)];
    for (int i = tid; i < 6 * 132; i += NTHR) {
        int t = i / 132, c = i % 132;
        hsw[i] = (c < HD) ? hsW1[(gi * 6 + t) * HD + c] : 0.f;
    }
    float b1v[8], b2v[8], b3v[8];
    float biR[8], bhR[8], biZ[8], bhZ[8], biN[8], bhN[8];
#pragma unroll
    for (int nt = 0; nt < 8; nt++) {
        int c = nt * 16 + lc;
        b1v[nt] = b1[gi * HD + c];
        b2v[nt] = b2[gi * HD + c];
        b3v[nt] = b3[gi * HD + c];
        biR[nt] = bih[gi * 384 + c];        bhR[nt] = bhh[gi * 384 + c];
        biZ[nt] = bih[gi * 384 + 128 + c];  bhZ[nt] = bhh[gi * 384 + 128 + c];
        biN[nt] = bih[gi * 384 + 256 + c];  bhN[nt] = bhh[gi * 384 + 256 + c];
    }

    grid_barrier(arr, rel, 1);   // becnt/epk/zcnt complete & visible

    // ---- stage this tile's per-level edge counts + level-1 zcnt ----
    if (tid >= 32 && tid < 39) ecs[tid - 32] = becnt[((tid - 32) * 3 + gi) * 64 + tilei];
    for (int i = tid; i < 512; i += NTHR)
        zs[i] = zcnt[((size_t)(gi * CAPN + tile)) * 8 + i];
    __syncthreads();

    const f32x4* zt4 = (const f32x4*)ztab;
    const unsigned short* WB = wbmlp + (size_t)gi * 3 * 16384;
    const unsigned short* WG = wbih + (size_t)gi * 49152;
    float* hfbuf = out + (size_t)NN * HD;

    // ---- fold level 1 msg accumulator from staged zcnt ----
    {
        int cnt1 = ncs[gi] > CAPN ? CAPN : ncs[gi];
        if (tile < cnt1) {
            for (int id = tid; id < 64 * 32; id += NTHR) {
                int row = id >> 5, lane = id & 31;
                f32x4 acc = {0.f, 0.f, 0.f, 0.f};
#pragma unroll
                for (int t = 0; t < 6; t++) {
                    int ct = zs[row * 8 + t];
                    if (ct) {
                        float f = (float)ct;
                        f32x4 z = zt4[(gi * 6 + t) * 32 + lane];
                        acc.x = fmaf(f, z.x, acc.x);
                        acc.y = fmaf(f, z.y, acc.y);
                        acc.z = fmaf(f, z.z, acc.z);
                        acc.w = fmaf(f, z.w, acc.w);
                    }
                }
                *(f32x4*)&msgf[row * MP + lane * 4] = acc;
            }
        }
    }
    __syncthreads();

    for (int l = 1; l <= 7; ++l) {
        const int glob = (l - 1) * 3 + gi;
        int cnt0 = ncs[glob]; if (cnt0 > CAPN) cnt0 = CAPN;
        const bool active = (tile < cnt0);
        if (active) {
            const int nv = min(64, cnt0 - tile);
            int ecb = ecs[l - 1]; if (ecb > CAPB) ecb = CAPB;
            if (ecb) {
                const int* ep = epk + (size_t)(glob * 64 + tilei) * CAPB;
                for (int c0 = 0; c0 < ecb; c0 += 64) {
                    int ne = min(64, ecb - c0);
                    // wave-local staging of hf[src] (bf16)
                    {
                        int row = rbase + (ln >> 2), q = ln & 3;
                        unsigned int* Au = (unsigned int*)A;
                        int base = (row * AP + q * 32) >> 1;
                        if (row < ne) {
                            int s = ep[c0 + row] & 0x1FFFF;
                            const float4* src4 = (const float4*)(hfbuf + (size_t)s * HD + q * 32);
#pragma unroll
                            for (int i = 0; i < 8; i++) {
                                float4 v = src4[i];
                                Au[base + i * 2]     = f2bf(v.x) | ((unsigned int)f2bf(v.y) << 16);
                                Au[base + i * 2 + 1] = f2bf(v.z) | ((unsigned int)f2bf(v.w) << 16);
                            }
                        } else {
#pragma unroll
                            for (int i = 0; i < 16; i++) Au[base + i] = 0u;
                        }
                    }
                    int sg = 0, lo = 0;
                    if (ln < 16) {
                        int r2 = rbase + ln;
                        if (r2 < ne) {
                            int p = ep[c0 + r2];
                            sg = (p >> 17) & 7;
                            lo = (p >> 23) & 63;
                        }
                    }

                    // layer 1: relu(hsW1[gate_src] + hf@W1bot + b1), in-place
                    {
                        bf16x8 af[4];
#pragma unroll
                        for (int kc = 0; kc < 4; kc++)
                            af[kc] = *(bf16x8*)&A[(rbase + lc) * AP + kc * 32 + quad * 8];
                        for (int nt = 0; nt < 8; nt++) {
                            f32x4 acc = {0.f, 0.f, 0.f, 0.f};
#pragma unroll
                            for (int kc = 0; kc < 4; kc++) {
                                bf16x8 bf = *(const bf16x8*)&WB[((nt * 4 + kc) * 64 + ln) * 8];
                                acc = __builtin_amdgcn_mfma_f32_16x16x32_bf16(af[kc], bf, acc, 0, 0, 0);
                            }
#pragma unroll
                            for (int r = 0; r < 4; r++) {
                                int row = rbase + quad * 4 + r;
                                int sgr = __shfl(sg, quad * 4 + r);
                                float v = acc[r] + hsw[sgr * 132 + nt * 16 + lc] + b1v[nt];
                                A[row * AP + nt * 16 + lc] = f2bf(fmaxf(v, 0.f));
                            }
                        }
                    }
                    // layer 2
                    {
                        bf16x8 af[4];
#pragma unroll
                        for (int kc = 0; kc < 4; kc++)
                            af[kc] = *(bf16x8*)&A[(rbase + lc) * AP + kc * 32 + quad * 8];
                        for (int nt = 0; nt < 8; nt++) {
                            f32x4 acc = {0.f, 0.f, 0.f, 0.f};
#pragma unroll
                            for (int kc = 0; kc < 4; kc++) {
                                bf16x8 bf = *(const bf16x8*)&WB[16384 + ((nt * 4 + kc) * 64 + ln) * 8];
                                acc = __builtin_amdgcn_mfma_f32_16x16x32_bf16(af[kc], bf, acc, 0, 0, 0);
                            }
#pragma unroll
                            for (int r = 0; r < 4; r++) {
                                int row = rbase + quad * 4 + r;
                                A[row * AP + nt * 16 + lc] = f2bf(fmaxf(acc[r] + b2v[nt], 0.f));
                            }
                        }
                    }
                    // layer 3 + LDS scatter-add into msgf
                    {
                        bf16x8 af[4];
#pragma unroll
                        for (int kc = 0; kc < 4; kc++)
                            af[kc] = *(bf16x8*)&A[(rbase + lc) * AP + kc * 32 + quad * 8];
                        for (int nt = 0; nt < 8; nt++) {
                            f32x4 acc = {0.f, 0.f, 0.f, 0.f};
#pragma unroll
                            for (int kc = 0; kc < 4; kc++) {
                                bf16x8 bf = *(const bf16x8*)&WB[2 * 16384 + ((nt * 4 + kc) * 64 + ln) * 8];
                                acc = __builtin_amdgcn_mfma_f32_16x16x32_bf16(af[kc], bf, acc, 0, 0, 0);
                            }
#pragma unroll
                            for (int r = 0; r < 4; r++) {
                                int row = rbase + quad * 4 + r;
                                if (row < ne) {
                                    int lr = __shfl(lo, quad * 4 + r);
                                    atomicAdd(&msgf[lr * MP + nt * 16 + lc], acc[r] + b3v[nt]);
                                }
                            }
                        }
                    }
                }
            }
            __syncthreads();   // edge atomics visible before GRU reads msgf

            // ---- GRU: gin = msg @ wih.T + bih ; gh = bhh (h_old == 0) ----
            int nd = -1;
            if (ln < 16) {
                int r2 = rbase + ln;
                nd = (r2 < nv) ? nls[(l - 1) * 64 + r2] : -1;
            }
            bf16x8 af[4];
#pragma unroll
            for (int kc = 0; kc < 4; kc++) {
                const float* mp = &msgf[(rbase + lc) * MP + kc * 32 + quad * 8];
                f32x4 v0 = *(const f32x4*)mp;
                f32x4 v1 = *(const f32x4*)(mp + 4);
                bf16x8 a;
                a[0] = (short)f2bf(v0.x); a[1] = (short)f2bf(v0.y);
                a[2] = (short)f2bf(v0.z); a[3] = (short)f2bf(v0.w);
                a[4] = (short)f2bf(v1.x); a[5] = (short)f2bf(v1.y);
                a[6] = (short)f2bf(v1.z); a[7] = (short)f2bf(v1.w);
                af[kc] = a;
            }
            for (int nt = 0; nt < 8; nt++) {
                f32x4 aR = {0.f, 0.f, 0.f, 0.f};
                f32x4 aZ = {0.f, 0.f, 0.f, 0.f};
                f32x4 aN = {0.f, 0.f, 0.f, 0.f};
#pragma unroll
                for (int kc = 0; kc < 4; kc++) {
                    bf16x8 bR = *(const bf16x8*)&WG[(((nt)      * 4 + kc) * 64 + ln) * 8];
                    bf16x8 bZ = *(const bf16x8*)&WG[(((nt + 8)  * 4 + kc) * 64 + ln) * 8];
                    bf16x8 bN = *(const bf16x8*)&WG[(((nt + 16) * 4 + kc) * 64 + ln) * 8];
                    aR = __builtin_amdgcn_mfma_f32_16x16x32_bf16(af[kc], bR, aR, 0, 0, 0);
                    aZ = __builtin_amdgcn_mfma_f32_16x16x32_bf16(af[kc], bZ, aZ, 0, 0, 0);
                    aN = __builtin_amdgcn_mfma_f32_16x16x32_bf16(af[kc], bN, aN, 0, 0, 0);
                }
                int c = nt * 16 + lc;
#pragma unroll
                for (int r = 0; r < 4; r++) {
                    int row = rbase + quad * 4 + r;
                    int n = __shfl(nd, quad * 4 + r);
                    if (n >= 0 && row < nv) {
                        float ir = aR[r] + biR[nt] + bhR[nt];
                        float iz = aZ[r] + biZ[nt] + bhZ[nt];
                        float inn = aN[r] + biN[nt];
                        float rg = 1.f / (1.f + expf(-ir));
                        float zg = 1.f / (1.f + expf(-iz));
                        float nst = tanhf(inn + rg * bhN[nt]);
                        hfbuf[(size_t)n * HD + c] = (1.f - zg) * nst;
                    }
                }
            }
        }

        if (l < 7) {
            __syncthreads();                 // all waves done reading msgf / zs
            // fold msg accumulator for level l+1 (independent of hf)
            const int globn = l * 3 + gi;
            for (int i = tid; i < 512; i += NTHR)
                zs[i] = zcnt[((size_t)(globn * CAPN + tile)) * 8 + i];
            __syncthreads();
            int cntn = ncs[globn]; if (cntn > CAPN) cntn = CAPN;
            if (tile < cntn) {
                for (int id = tid; id < 64 * 32; id += NTHR) {
                    int row = id >> 5, lane = id & 31;
                    f32x4 acc = {0.f, 0.f, 0.f, 0.f};
#pragma unroll
                    for (int t = 0; t < 6; t++) {
                        int ct = zs[row * 8 + t];
                        if (ct) {
                            float f = (float)ct;
                            f32x4 z = zt4[(gi * 6 + t) * 32 + lane];
                            acc.x = fmaf(f, z.x, acc.x);
                            acc.y = fmaf(f, z.y, acc.y);
                            acc.z = fmaf(f, z.z, acc.z);
                            acc.w = fmaf(f, z.w, acc.w);
                        }
                    }
                    *(f32x4*)&msgf[row * MP + lane * 4] = acc;
                }
            }
            grid_barrier(arr, rel, l + 1);   // hf stores flushed; next level may gather
        }
    }
}

extern "C" void kernel_launch(void* const* d_in, const int* in_sizes, int n_in,
                              void* d_out, int out_size, void* d_ws, size_t ws_size,
                              hipStream_t stream) {
    const int* gate = (const int*)d_in[0];
    const int* lvl  = (const int*)d_in[1];
    const int* ei   = (const int*)d_in[2];
    const float* Ws   = (const float*)d_in[3];
    const float* Wt   = (const float*)d_in[4];
    const float* hs_W = (const float*)d_in[5];
    const float* hs_b = (const float*)d_in[6];
    const float* w1 = (const float*)d_in[7];
    const float* b1 = (const float*)d_in[8];
    const float* w2 = (const float*)d_in[9];
    const float* b2 = (const float*)d_in[10];
    const float* w3 = (const float*)d_in[11];
    const float* b3 = (const float*)d_in[12];
    const float* wih = (const float*)d_in[13];
    // d_in[14] = gru_whh: unused (h_old provably zero for every updated node)
    const float* bih = (const float*)d_in[15];
    const float* bhh = (const float*)d_in[16];
    float* out = (float*)d_out;
    char* ws = (char*)d_ws;

    int*   ncnt    = (int*)(ws + OFF_NCNT);
    int*   arr     = (int*)(ws + OFF_ARR);
    int*   rel     = (int*)(ws + OFF_REL);
    int*   becnt   = (int*)(ws + OFF_BECNT);
    int*   zcnt    = (int*)(ws + OFF_ZCNT);
    float* hs_type = (float*)(ws + OFF_HSTYPE);
    float* hsW1    = (float*)(ws + OFF_HSW1);
    float* ztab    = (float*)(ws + OFF_ZTAB);
    unsigned short* wbmlp = (unsigned short*)(ws + OFF_WBMLP);
    unsigned short* wbih  = (unsigned short*)(ws + OFF_WBIH);
    int*   nlist   = (int*)(ws + OFF_NLIST);
    int*   nslot   = (int*)(ws + OFF_NSLOT);
    int*   epk     = (int*)(ws + OFF_EPK);

    hipMemsetAsync(ws, 0, MEMSET_BYTES, stream);

    prep1_kernel<<<256, NTHR, 0, stream>>>(gate, lvl, Ws, Wt, hs_W, hs_b,
                                           w1, b1, w2, b2, w3, b3, wih,
                                           hs_type, hsW1, ztab, wbmlp, wbih,
                                           ncnt, nlist, nslot);

    levels_kernel<<<NBLK, NTHR, 0, stream>>>(gate, lvl, ei, nslot, hs_type,
                                             ncnt, nlist, becnt, epk, zcnt,
                                             ztab, hsW1, wbmlp, wbih,
                                             b1, b2, b3, bih, bhh,
                                             arr, rel, out);
}

// Round 5
// 501.144 us; speedup vs baseline: 1.7351x; 1.0078x over previous
//
#include <hip/hip_runtime.h>
#include <math.h>

#define NN 100000
#define NE 200000
#define HD 128
#define CAPN 4096
#define CAPB 256
#define NGROUP 21
#define NBLK 192
#define BSTRIDE 32   // barrier slot stride in ints (128 B)
#define AP 136   // bf16 LDS row pitch (shorts)
#define MP 132   // f32 LDS msg row pitch
#define NTHR 256

typedef short bf16x8 __attribute__((ext_vector_type(8)));
typedef float f32x4 __attribute__((ext_vector_type(4)));

// workspace byte offsets
#define OFF_NCNT   0                // 21 ints (pad to 128)
#define OFF_ARR    128              // 192*32 ints: arrive slots (128B apart)
#define OFF_REL    24704            // 192*32 ints: release slots
#define OFF_BECNT  49280            // 1344 ints (live edges per (group,dst-tile) bucket)
#define OFF_ZCNT   54656            // 21*4096*8 ints (zero-edge counts per dst,src-gate)
#define MEMSET_BYTES 2807168        // covers ncnt+arr+rel+becnt+zcnt
#define OFF_HSTYPE 2807168          // 6*128 f32
#define OFF_HSW1   2810240          // 3*6*128 f32
#define OFF_ZTAB   2819456          // 3*6*128 f32 (msg of a zero-hf src, per gi,src-gate)
#define OFF_WBMLP  2828672          // 3*3*16384 bf16 swizzled B-frags
#define OFF_WBIH   3123584          // 3*49152 bf16 swizzled B-frags
#define OFF_NLIST  3418496          // 21*4096 ints
#define OFF_NSLOT  3762560          // NN ints
#define OFF_EPK    4162560          // 1344*256 ints: src | gate<<17 | localslot<<23

#define SWTOT (3 * 3 * 16384 + 3 * 49152)

__device__ __forceinline__ int gi_of(int g) {
    return (g == 3) ? 0 : (g == 2) ? 1 : (g == 5) ? 2 : -1;
}

__device__ __forceinline__ unsigned short f2bf(float f) {
    unsigned int u = __float_as_uint(f);
    u += 0x7FFF + ((u >> 16) & 1);   // RNE
    return (unsigned short)(u >> 16);
}

// Distributed grid barrier (graph-capture-safe; 192 blocks <= 256 CUs so all
// blocks are always resident -> no deadlock). Arrive: each block RELEASE-
// stores its own 128B-strided slot. Master block polls 191 DISTINCT lines
// with RELAXED loads (no same-line queueing), then RELEASE-stores per-block
// release slots. Workers poll only their own slot. One agent-acquire fence
// at exit drops stale clean lines (needed for hf rows written on other XCDs).
__device__ __forceinline__ void grid_barrier(int* arr, int* rel, int phase) {
    __syncthreads();   // all block stores drained before arrival
    const int tid = threadIdx.x;
    const int bid = blockIdx.x;
    if (bid == 0) {
        if (tid >= 1 && tid < NBLK) {
            while (__hip_atomic_load(&arr[tid * BSTRIDE], __ATOMIC_RELAXED,
                                     __HIP_MEMORY_SCOPE_AGENT) < phase)
                __builtin_amdgcn_s_sleep(2);
        }
        __syncthreads();                     // all arrivals observed
        if (tid >= 1 && tid < NBLK)
            __hip_atomic_store(&rel[tid * BSTRIDE], phase, __ATOMIC_RELEASE,
                               __HIP_MEMORY_SCOPE_AGENT);
    } else {
        if (tid == 0) {
            __hip_atomic_store(&arr[bid * BSTRIDE], phase, __ATOMIC_RELEASE,
                               __HIP_MEMORY_SCOPE_AGENT);
            while (__hip_atomic_load(&rel[bid * BSTRIDE], __ATOMIC_RELAXED,
                                     __HIP_MEMORY_SCOPE_AGENT) < phase)
                __builtin_amdgcn_s_sleep(2);
        }
    }
    __builtin_amdgcn_fence(__ATOMIC_ACQUIRE, "agent");
    __syncthreads();
}

// ---------------------------------------------------------------------------
// prep1: block 0 -> hs_type + hsW1; blocks 1..18 -> ztab rows (self-contained);
// blocks 19+ -> weight swizzle + group_nodes (LDS-aggregated).
// ---------------------------------------------------------------------------
__global__ __launch_bounds__(NTHR) void prep1_kernel(
    const int* __restrict__ gate, const int* __restrict__ lvl,
    const float* __restrict__ Ws, const float* __restrict__ Wt,
    const float* __restrict__ hs_W, const float* __restrict__ hs_b,
    const float* __restrict__ w1, const float* __restrict__ b1,
    const float* __restrict__ w2, const float* __restrict__ b2,
    const float* __restrict__ w3, const float* __restrict__ b3,
    const float* __restrict__ wih,
    float* __restrict__ hs_type, float* __restrict__ hsW1,
    float* __restrict__ ztab,
    unsigned short* __restrict__ wbmlp, unsigned short* __restrict__ wbih,
    int* __restrict__ ncnt, int* __restrict__ nlist, int* __restrict__ nslot) {
    __shared__ float lht[6 * HD];
    __shared__ float s0[HD], s1[HD], s2[HD];
    __shared__ int lcnt[NGROUP], lbase[NGROUP];
    const int bid = blockIdx.x, tid = threadIdx.x;

    if (bid == 0) {
        for (int idx = tid; idx < 6 * HD; idx += NTHR) {
            int t = idx >> 7, c = idx & 127;
            float acc = hs_b[c];
            for (int k = 0; k < HD; k++) acc = fmaf(Ws[t * HD + k], hs_W[k * HD + c], acc);
            for (int k = 0; k < HD; k++) acc = fmaf(Wt[t * HD + k], hs_W[(HD + k) * HD + c], acc);
            lht[idx] = acc;
            hs_type[idx] = acc;
        }
        __syncthreads();
        for (int idx = tid; idx < 3 * 6 * HD; idx += NTHR) {
            int gi = idx / (6 * HD);
            int t = (idx >> 7) % 6;
            int c = idx & 127;
            const float* w = w1 + gi * (2 * HD * HD);  // top half rows 0..127
            float acc = 0.f;
            for (int k = 0; k < HD; k++) acc = fmaf(lht[t * HD + k], w[k * HD + c], acc);
            hsW1[idx] = acc;
        }
    } else if (bid <= 18) {
        // ztab[gi][t] = MLP_gi([hs_type[t], 0]) — fp32, self-contained
        int gi = (bid - 1) / 6, t = (bid - 1) % 6;
        int c = tid;
        if (c < HD) {
            float acc = hs_b[c];
            for (int k = 0; k < HD; k++) acc = fmaf(Ws[t * HD + k], hs_W[k * HD + c], acc);
            for (int k = 0; k < HD; k++) acc = fmaf(Wt[t * HD + k], hs_W[(HD + k) * HD + c], acc);
            s0[c] = acc;
        }
        __syncthreads();
        if (c < HD) {
            const float* w = w1 + gi * (2 * HD * HD);  // top half
            float acc = b1[gi * HD + c];
            for (int k = 0; k < HD; k++) acc = fmaf(s0[k], w[k * HD + c], acc);
            s1[c] = fmaxf(acc, 0.f);
        }
        __syncthreads();
        if (c < HD) {
            const float* w = w2 + gi * (HD * HD);
            float acc = b2[gi * HD + c];
            for (int k = 0; k < HD; k++) acc = fmaf(s1[k], w[k * HD + c], acc);
            s2[c] = fmaxf(acc, 0.f);
        }
        __syncthreads();
        if (c < HD) {
            const float* w = w3 + gi * (HD * HD);
            float acc = b3[gi * HD + c];
            for (int k = 0; k < HD; k++) acc = fmaf(s2[k], w[k * HD + c], acc);
            ztab[(gi * 6 + t) * HD + c] = acc;
        }
    } else {
        const int nb = gridDim.x - 19;          // worker blocks
        const int wb = bid - 19;
        // weight swizzle into MFMA B-fragment layout
        for (int id = wb * NTHR + tid; id < SWTOT; id += nb * NTHR) {
            if (id < 3 * 3 * 16384) {
                int gi = id / 49152;
                int rem = id % 49152;
                int layer = rem / 16384;
                int e = rem % 16384;
                int k = e >> 7, n = e & 127;
                float v;
                if (layer == 0)      v = w1[gi * (2 * HD * HD) + (HD + k) * HD + n];
                else if (layer == 1) v = w2[gi * (HD * HD) + k * HD + n];
                else                 v = w3[gi * (HD * HD) + k * HD + n];
                int nt = n >> 4, kc = k >> 5, kq = (k >> 3) & 3, j = k & 7;
                int L = (kq << 4) | (n & 15);
                wbmlp[(size_t)(gi * 3 + layer) * 16384 + ((nt * 4 + kc) * 64 + L) * 8 + j] = f2bf(v);
            } else {
                int id2 = id - 3 * 3 * 16384;
                int gi = id2 / 49152;
                int e = id2 % 49152;
                int k = e / 384, n = e % 384;             // B[k][n] = wih[n][k]
                float v = wih[gi * (384 * HD) + n * HD + k];
                int nt = n >> 4, kc = k >> 5, kq = (k >> 3) & 3, j = k & 7;
                int L = (kq << 4) | (n & 15);
                wbih[(size_t)gi * 49152 + ((nt * 4 + kc) * 64 + L) * 8 + j] = f2bf(v);
            }
        }
        // group_nodes (LDS-aggregated)
        for (int base = wb * NTHR; base < NN; base += nb * NTHR) {
            if (tid < NGROUP) lcnt[tid] = 0;
            __syncthreads();
            int i = base + tid;
            int glob = -1, local = 0;
            if (i < NN) {
                int gi = gi_of(gate[i]);
                int l = lvl[i];
                if (gi >= 0 && l >= 1) {
                    glob = (l - 1) * 3 + gi;
                    local = atomicAdd(&lcnt[glob], 1);
                }
            }
            __syncthreads();
            if (tid < NGROUP) {
                int cc = lcnt[tid];
                lbase[tid] = cc ? atomicAdd(&ncnt[tid], cc) : 0;
            }
            __syncthreads();
            if (glob >= 0) {
                int slot = lbase[glob] + local;
                if (slot < CAPN) {
                    nlist[glob * CAPN + slot] = i;
                    nslot[i] = slot;
                }
            }
            __syncthreads();
        }
    }
}

// ---------------------------------------------------------------------------
// prep2: hs scatter (hf half is zeroed by hipMemsetAsync) + edge classify.
// Live edges -> per-(group, dst-tile) bucket, packed src|gate|localslot.
// Zero-hf edges -> one int atomicAdd into zcnt[(glob,dslot,src_gate)].
// High-occupancy streaming kernel: 1024 blocks.
// ---------------------------------------------------------------------------
__global__ __launch_bounds__(NTHR) void prep2_kernel(
    const int* __restrict__ gate, const int* __restrict__ lvl,
    const int* __restrict__ ei, const int* __restrict__ nslot,
    const float* __restrict__ hs_type, float* __restrict__ out,
    int* __restrict__ becnt, int* __restrict__ epk,
    int* __restrict__ zcnt) {
    const int stride = gridDim.x * NTHR;
    const int tid0 = blockIdx.x * NTHR + threadIdx.x;

    const float4* ht4 = (const float4*)hs_type;
    float4* o4 = (float4*)out;
    for (int idx = tid0; idx < NN * 32; idx += stride) {
        int i = idx >> 5, q = idx & 31;
        o4[idx] = ht4[gate[i] * 32 + q];
    }

    for (int e = tid0; e < NE; e += stride) {
        int d = ei[NE + e];
        int gd = gi_of(gate[d]);
        int ld = lvl[d];
        if (gd < 0 || ld < 1) continue;
        int g = (ld - 1) * 3 + gd;
        int s = ei[e];
        int dsl = nslot[d];
        int gs = gate[s], ls = lvl[s];
        bool live = (gi_of(gs) >= 0) && (ls >= 1) && (ls < ld);
        if (live) {
            int bucket = g * 64 + (dsl >> 6);
            int slot = atomicAdd(&becnt[bucket], 1);
            if (slot < CAPB)
                epk[(size_t)bucket * CAPB + slot] = s | (gs << 17) | ((dsl & 63) << 23);
        } else {
            atomicAdd(&zcnt[((size_t)g * CAPN + dsl) * 8 + gs], 1);
        }
    }
}

// ---------------------------------------------------------------------------
// levels_kernel: persistent, ONLY the 7 levels + 6 distributed barriers.
// Block (gi,tilei) owns dst slots [tile,tile+64) of group gi at every level.
// ztab fold for the NEXT level is computed before the barrier (independent
// of hf), keeping the inter-barrier critical path at gather->MFMA->store.
// ---------------------------------------------------------------------------
__global__ __launch_bounds__(NTHR) void levels_kernel(
    const int* ncnt, const int* nlist, const int* becnt, const int* epk,
    const int* zcnt, const float* ztab, const float* hsW1,
    const unsigned short* wbmlp, const unsigned short* wbih,
    const float* b1, const float* b2, const float* b3,
    const float* bih, const float* bhh,
    int* arr, int* rel, float* out) {
    __shared__ unsigned short A[64 * AP];   // 17408 B
    __shared__ float msgf[64 * MP];         // 33792 B
    __shared__ float hsw[6 * 132];          // 3168 B
    __shared__ int zs[64 * 8];              // 2048 B
    __shared__ int nls[7 * 64];             // 1792 B
    __shared__ int ncs[24];
    __shared__ int ecs[8];

    const int gi = blockIdx.x >> 6;
    const int tilei = blockIdx.x & 63;
    const int tile = tilei * 64;
    const int tid = threadIdx.x;
    const int ln = tid & 63, wv = tid >> 6;
    const int lc = ln & 15, quad = ln >> 4;
    const int rbase = wv * 16;

    // ---- prologue: stage all per-block metadata once ----
    if (tid < NGROUP) ncs[tid] = ncnt[tid];
    if (tid >= 32 && tid < 39) ecs[tid - 32] = becnt[((tid - 32) * 3 + gi) * 64 + tilei];
    for (int i = tid; i < 7 * 64; i += NTHR)
        nls[i] = nlist[((i >> 6) * 3 + gi) * CAPN + tile + (i & 63)];
    for (int i = tid; i < 6 * 132; i += NTHR) {
        int t = i / 132, c = i % 132;
        hsw[i] = (c < HD) ? hsW1[(gi * 6 + t) * HD + c] : 0.f;
    }
    for (int i = tid; i < 512; i += NTHR)                       // level-1 zcnt (glob = gi)
        zs[i] = zcnt[((size_t)(gi * CAPN + tile)) * 8 + i];

    float b1v[8], b2v[8], b3v[8];
    float biR[8], bhR[8], biZ[8], bhZ[8], biN[8], bhN[8];
#pragma unroll
    for (int nt = 0; nt < 8; nt++) {
        int c = nt * 16 + lc;
        b1v[nt] = b1[gi * HD + c];
        b2v[nt] = b2[gi * HD + c];
        b3v[nt] = b3[gi * HD + c];
        biR[nt] = bih[gi * 384 + c];        bhR[nt] = bhh[gi * 384 + c];
        biZ[nt] = bih[gi * 384 + 128 + c];  bhZ[nt] = bhh[gi * 384 + 128 + c];
        biN[nt] = bih[gi * 384 + 256 + c];  bhN[nt] = bhh[gi * 384 + 256 + c];
    }
    __syncthreads();

    const f32x4* zt4 = (const f32x4*)ztab;
    const unsigned short* WB = wbmlp + (size_t)gi * 3 * 16384;
    const unsigned short* WG = wbih + (size_t)gi * 49152;
    float* hfbuf = out + (size_t)NN * HD;

    // ---- fold level 1 msg accumulator from staged zcnt ----
    {
        int cnt1 = ncs[gi] > CAPN ? CAPN : ncs[gi];
        if (tile < cnt1) {
            for (int id = tid; id < 64 * 32; id += NTHR) {
                int row = id >> 5, lane = id & 31;
                f32x4 acc = {0.f, 0.f, 0.f, 0.f};
#pragma unroll
                for (int t = 0; t < 6; t++) {
                    int ct = zs[row * 8 + t];
                    if (ct) {
                        float f = (float)ct;
                        f32x4 z = zt4[(gi * 6 + t) * 32 + lane];
                        acc.x = fmaf(f, z.x, acc.x);
                        acc.y = fmaf(f, z.y, acc.y);
                        acc.z = fmaf(f, z.z, acc.z);
                        acc.w = fmaf(f, z.w, acc.w);
                    }
                }
                *(f32x4*)&msgf[row * MP + lane * 4] = acc;
            }
        }
    }
    __syncthreads();

    for (int l = 1; l <= 7; ++l) {
        const int glob = (l - 1) * 3 + gi;
        int cnt0 = ncs[glob]; if (cnt0 > CAPN) cnt0 = CAPN;
        const bool active = (tile < cnt0);
        if (active) {
            const int nv = min(64, cnt0 - tile);
            int ecb = ecs[l - 1]; if (ecb > CAPB) ecb = CAPB;
            if (ecb) {
                const int* ep = epk + (size_t)(glob * 64 + tilei) * CAPB;
                for (int c0 = 0; c0 < ecb; c0 += 64) {
                    int ne = min(64, ecb - c0);
                    // wave-local staging of hf[src] (bf16)
                    {
                        int row = rbase + (ln >> 2), q = ln & 3;
                        unsigned int* Au = (unsigned int*)A;
                        int base = (row * AP + q * 32) >> 1;
                        if (row < ne) {
                            int s = ep[c0 + row] & 0x1FFFF;
                            const float4* src4 = (const float4*)(hfbuf + (size_t)s * HD + q * 32);
#pragma unroll
                            for (int i = 0; i < 8; i++) {
                                float4 v = src4[i];
                                Au[base + i * 2]     = f2bf(v.x) | ((unsigned int)f2bf(v.y) << 16);
                                Au[base + i * 2 + 1] = f2bf(v.z) | ((unsigned int)f2bf(v.w) << 16);
                            }
                        } else {
#pragma unroll
                            for (int i = 0; i < 16; i++) Au[base + i] = 0u;
                        }
                    }
                    int sg = 0, lo = 0;
                    if (ln < 16) {
                        int r2 = rbase + ln;
                        if (r2 < ne) {
                            int p = ep[c0 + r2];
                            sg = (p >> 17) & 7;
                            lo = (p >> 23) & 63;
                        }
                    }

                    // layer 1: relu(hsW1[gate_src] + hf@W1bot + b1), in-place
                    {
                        bf16x8 af[4];
#pragma unroll
                        for (int kc = 0; kc < 4; kc++)
                            af[kc] = *(bf16x8*)&A[(rbase + lc) * AP + kc * 32 + quad * 8];
                        for (int nt = 0; nt < 8; nt++) {
                            f32x4 acc = {0.f, 0.f, 0.f, 0.f};
#pragma unroll
                            for (int kc = 0; kc < 4; kc++) {
                                bf16x8 bf = *(const bf16x8*)&WB[((nt * 4 + kc) * 64 + ln) * 8];
                                acc = __builtin_amdgcn_mfma_f32_16x16x32_bf16(af[kc], bf, acc, 0, 0, 0);
                            }
#pragma unroll
                            for (int r = 0; r < 4; r++) {
                                int row = rbase + quad * 4 + r;
                                int sgr = __shfl(sg, quad * 4 + r);
                                float v = acc[r] + hsw[sgr * 132 + nt * 16 + lc] + b1v[nt];
                                A[row * AP + nt * 16 + lc] = f2bf(fmaxf(v, 0.f));
                            }
                        }
                    }
                    // layer 2
                    {
                        bf16x8 af[4];
#pragma unroll
                        for (int kc = 0; kc < 4; kc++)
                            af[kc] = *(bf16x8*)&A[(rbase + lc) * AP + kc * 32 + quad * 8];
                        for (int nt = 0; nt < 8; nt++) {
                            f32x4 acc = {0.f, 0.f, 0.f, 0.f};
#pragma unroll
                            for (int kc = 0; kc < 4; kc++) {
                                bf16x8 bf = *(const bf16x8*)&WB[16384 + ((nt * 4 + kc) * 64 + ln) * 8];
                                acc = __builtin_amdgcn_mfma_f32_16x16x32_bf16(af[kc], bf, acc, 0, 0, 0);
                            }
#pragma unroll
                            for (int r = 0; r < 4; r++) {
                                int row = rbase + quad * 4 + r;
                                A[row * AP + nt * 16 + lc] = f2bf(fmaxf(acc[r] + b2v[nt], 0.f));
                            }
                        }
                    }
                    // layer 3 + LDS scatter-add into msgf
                    {
                        bf16x8 af[4];
#pragma unroll
                        for (int kc = 0; kc < 4; kc++)
                            af[kc] = *(bf16x8*)&A[(rbase + lc) * AP + kc * 32 + quad * 8];
                        for (int nt = 0; nt < 8; nt++) {
                            f32x4 acc = {0.f, 0.f, 0.f, 0.f};
#pragma unroll
                            for (int kc = 0; kc < 4; kc++) {
                                bf16x8 bf = *(const bf16x8*)&WB[2 * 16384 + ((nt * 4 + kc) * 64 + ln) * 8];
                                acc = __builtin_amdgcn_mfma_f32_16x16x32_bf16(af[kc], bf, acc, 0, 0, 0);
                            }
#pragma unroll
                            for (int r = 0; r < 4; r++) {
                                int row = rbase + quad * 4 + r;
                                if (row < ne) {
                                    int lr = __shfl(lo, quad * 4 + r);
                                    atomicAdd(&msgf[lr * MP + nt * 16 + lc], acc[r] + b3v[nt]);
                                }
                            }
                        }
                    }
                }
            }
            __syncthreads();   // edge atomics visible before GRU reads msgf

            // ---- GRU: gin = msg @ wih.T + bih ; gh = bhh (h_old == 0) ----
            int nd = -1;
            if (ln < 16) {
                int r2 = rbase + ln;
                nd = (r2 < nv) ? nls[(l - 1) * 64 + r2] : -1;
            }
            bf16x8 af[4];
#pragma unroll
            for (int kc = 0; kc < 4; kc++) {
                const float* mp = &msgf[(rbase + lc) * MP + kc * 32 + quad * 8];
                f32x4 v0 = *(const f32x4*)mp;
                f32x4 v1 = *(const f32x4*)(mp + 4);
                bf16x8 a;
                a[0] = (short)f2bf(v0.x); a[1] = (short)f2bf(v0.y);
                a[2] = (short)f2bf(v0.z); a[3] = (short)f2bf(v0.w);
                a[4] = (short)f2bf(v1.x); a[5] = (short)f2bf(v1.y);
                a[6] = (short)f2bf(v1.z); a[7] = (short)f2bf(v1.w);
                af[kc] = a;
            }
            for (int nt = 0; nt < 8; nt++) {
                f32x4 aR = {0.f, 0.f, 0.f, 0.f};
                f32x4 aZ = {0.f, 0.f, 0.f, 0.f};
                f32x4 aN = {0.f, 0.f, 0.f, 0.f};
#pragma unroll
                for (int kc = 0; kc < 4; kc++) {
                    bf16x8 bR = *(const bf16x8*)&WG[(((nt)      * 4 + kc) * 64 + ln) * 8];
                    bf16x8 bZ = *(const bf16x8*)&WG[(((nt + 8)  * 4 + kc) * 64 + ln) * 8];
                    bf16x8 bN = *(const bf16x8*)&WG[(((nt + 16) * 4 + kc) * 64 + ln) * 8];
                    aR = __builtin_amdgcn_mfma_f32_16x16x32_bf16(af[kc], bR, aR, 0, 0, 0);
                    aZ = __builtin_amdgcn_mfma_f32_16x16x32_bf16(af[kc], bZ, aZ, 0, 0, 0);
                    aN = __builtin_amdgcn_mfma_f32_16x16x32_bf16(af[kc], bN, aN, 0, 0, 0);
                }
                int c = nt * 16 + lc;
#pragma unroll
                for (int r = 0; r < 4; r++) {
                    int row = rbase + quad * 4 + r;
                    int n = __shfl(nd, quad * 4 + r);
                    if (n >= 0 && row < nv) {
                        float ir = aR[r] + biR[nt] + bhR[nt];
                        float iz = aZ[r] + biZ[nt] + bhZ[nt];
                        float inn = aN[r] + biN[nt];
                        float rg = 1.f / (1.f + expf(-ir));
                        float zg = 1.f / (1.f + expf(-iz));
                        float nst = tanhf(inn + rg * bhN[nt]);
                        hfbuf[(size_t)n * HD + c] = (1.f - zg) * nst;
                    }
                }
            }
        }

        if (l < 7) {
            __syncthreads();                 // all waves done reading msgf / zs
            // fold msg accumulator for level l+1 (independent of hf)
            const int globn = l * 3 + gi;
            for (int i = tid; i < 512; i += NTHR)
                zs[i] = zcnt[((size_t)(globn * CAPN + tile)) * 8 + i];
            __syncthreads();
            int cntn = ncs[globn]; if (cntn > CAPN) cntn = CAPN;
            if (tile < cntn) {
                for (int id = tid; id < 64 * 32; id += NTHR) {
                    int row = id >> 5, lane = id & 31;
                    f32x4 acc = {0.f, 0.f, 0.f, 0.f};
#pragma unroll
                    for (int t = 0; t < 6; t++) {
                        int ct = zs[row * 8 + t];
                        if (ct) {
                            float f = (float)ct;
                            f32x4 z = zt4[(gi * 6 + t) * 32 + lane];
                            acc.x = fmaf(f, z.x, acc.x);
                            acc.y = fmaf(f, z.y, acc.y);
                            acc.z = fmaf(f, z.z, acc.z);
                            acc.w = fmaf(f, z.w, acc.w);
                        }
                    }
                    *(f32x4*)&msgf[row * MP + lane * 4] = acc;
                }
            }
            grid_barrier(arr, rel, l);       // hf stores flushed; next level may gather
        }
    }
}

extern "C" void kernel_launch(void* const* d_in, const int* in_sizes, int n_in,
                              void* d_out, int out_size, void* d_ws, size_t ws_size,
                              hipStream_t stream) {
    const int* gate = (const int*)d_in[0];
    const int* lvl  = (const int*)d_in[1];
    const int* ei   = (const int*)d_in[2];
    const float* Ws   = (const float*)d_in[3];
    const float* Wt   = (const float*)d_in[4];
    const float* hs_W = (const float*)d_in[5];
    const float* hs_b = (const float*)d_in[6];
    const float* w1 = (const float*)d_in[7];
    const float* b1 = (const float*)d_in[8];
    const float* w2 = (const float*)d_in[9];
    const float* b2 = (const float*)d_in[10];
    const float* w3 = (const float*)d_in[11];
    const float* b3 = (const float*)d_in[12];
    const float* wih = (const float*)d_in[13];
    // d_in[14] = gru_whh: unused (h_old provably zero for every updated node)
    const float* bih = (const float*)d_in[15];
    const float* bhh = (const float*)d_in[16];
    float* out = (float*)d_out;
    char* ws = (char*)d_ws;

    int*   ncnt    = (int*)(ws + OFF_NCNT);
    int*   arr     = (int*)(ws + OFF_ARR);
    int*   rel     = (int*)(ws + OFF_REL);
    int*   becnt   = (int*)(ws + OFF_BECNT);
    int*   zcnt    = (int*)(ws + OFF_ZCNT);
    float* hs_type = (float*)(ws + OFF_HSTYPE);
    float* hsW1    = (float*)(ws + OFF_HSW1);
    float* ztab    = (float*)(ws + OFF_ZTAB);
    unsigned short* wbmlp = (unsigned short*)(ws + OFF_WBMLP);
    unsigned short* wbih  = (unsigned short*)(ws + OFF_WBIH);
    int*   nlist   = (int*)(ws + OFF_NLIST);
    int*   nslot   = (int*)(ws + OFF_NSLOT);
    int*   epk     = (int*)(ws + OFF_EPK);

    hipMemsetAsync(ws, 0, MEMSET_BYTES, stream);
    // hf half of the output: zero via fill engine (fill kernels run ~6.6 TB/s)
    hipMemsetAsync(out + (size_t)NN * HD, 0, (size_t)NN * HD * sizeof(float), stream);

    prep1_kernel<<<256, NTHR, 0, stream>>>(gate, lvl, Ws, Wt, hs_W, hs_b,
                                           w1, b1, w2, b2, w3, b3, wih,
                                           hs_type, hsW1, ztab, wbmlp, wbih,
                                           ncnt, nlist, nslot);
    prep2_kernel<<<1024, NTHR, 0, stream>>>(gate, lvl, ei, nslot, hs_type, out,
                                            becnt, epk, zcnt);

    levels_kernel<<<NBLK, NTHR, 0, stream>>>(ncnt, nlist, becnt, epk, zcnt,
                                             ztab, hsW1, wbmlp, wbih,
                                             b1, b2, b3, bih, bhh,
                                             arr, rel, out);
}

// Round 6
// 479.467 us; speedup vs baseline: 1.8135x; 1.0452x over previous
//
#include <hip/hip_runtime.h>
#include <math.h>

#define NN 100000
#define NE 200000
#define HD 128
#define CAPN 4096
#define CAPB 256
#define NGROUP 21
#define NBLK 192
#define BSTRIDE 32   // barrier slot stride in ints (128 B)
#define AP 136   // bf16 LDS row pitch (shorts)
#define MP 132   // f32 LDS msg row pitch
#define NTHR 256

typedef short bf16x8 __attribute__((ext_vector_type(8)));
typedef float f32x4 __attribute__((ext_vector_type(4)));

// workspace byte offsets
#define OFF_NCNT   0                // 21 ints (pad to 128)
#define OFF_ARR    128              // 192*32 ints: arrive slots (128B apart)
#define OFF_REL    24704            // 192*32 ints: release slots
#define OFF_BECNT  49280            // 1344 ints (live edges per (group,dst-tile) bucket)
#define OFF_ZCNT   54656            // 21*4096*8 ints (zero-edge counts per dst,src-gate)
#define MEMSET_BYTES 2807168        // covers ncnt+arr+rel+becnt+zcnt
#define OFF_HSTYPE 2807168          // 6*128 f32
#define OFF_HSW1   2810240          // 3*6*128 f32
#define OFF_ZTAB   2819456          // 3*6*128 f32 (msg of a zero-hf src, per gi,src-gate)
#define OFF_WBMLP  2828672          // 3*3*16384 bf16 swizzled B-frags
#define OFF_WBIH   3123584          // 3*49152 bf16 swizzled B-frags
#define OFF_NLIST  3418496          // 21*4096 ints
#define OFF_NSLOT  3762560          // NN ints
#define OFF_EPK    4162560          // 1344*256 ints: src | gate<<17 | localslot<<23

#define SWTOT (3 * 3 * 16384 + 3 * 49152)

__device__ __forceinline__ int gi_of(int g) {
    return (g == 3) ? 0 : (g == 2) ? 1 : (g == 5) ? 2 : -1;
}

__device__ __forceinline__ unsigned short f2bf(float f) {
    unsigned int u = __float_as_uint(f);
    u += 0x7FFF + ((u >> 16) & 1);   // RNE
    return (unsigned short)(u >> 16);
}

__device__ __forceinline__ unsigned int f2bfu(unsigned int u) {
    u += 0x7FFF + ((u >> 16) & 1);   // RNE on raw float bits
    return u >> 16;
}

// Agent-coherent (sc1, L2-read/write-through) 8-byte load / 4-byte store.
// These keep hf coherent across XCDs WITHOUT barrier-time buffer_inv/wbl2,
// so weights/epk/zcnt stay warm in each XCD L2 across all 7 levels.
__device__ __forceinline__ unsigned long long coh_load8(const unsigned long long* p) {
    return __hip_atomic_load(p, __ATOMIC_RELAXED, __HIP_MEMORY_SCOPE_AGENT);
}
__device__ __forceinline__ void coh_store4(float* p, float v) {
    __hip_atomic_store((unsigned int*)p, __float_as_uint(v),
                       __ATOMIC_RELAXED, __HIP_MEMORY_SCOPE_AGENT);
}

// Distributed grid barrier, PURE flag exchange (no fences). hf coherence is
// carried by the sc1 loads/stores above; __syncthreads() before arrival
// drains vmcnt(0) so all write-through hf stores completed. Master polls 191
// DISTINCT 128B-strided lines with relaxed agent loads (round-3 lesson: one
// shared line serializes ~190 deep). 192 blocks <= 256 CUs -> always
// co-resident -> no deadlock.
__device__ __forceinline__ void grid_barrier(int* arr, int* rel, int phase) {
    __syncthreads();   // all block stores drained before arrival
    const int tid = threadIdx.x;
    const int bid = blockIdx.x;
    if (bid == 0) {
        if (tid >= 1 && tid < NBLK) {
            while (__hip_atomic_load(&arr[tid * BSTRIDE], __ATOMIC_RELAXED,
                                     __HIP_MEMORY_SCOPE_AGENT) < phase)
                __builtin_amdgcn_s_sleep(2);
        }
        __syncthreads();                     // all arrivals observed
        if (tid >= 1 && tid < NBLK)
            __hip_atomic_store(&rel[tid * BSTRIDE], phase, __ATOMIC_RELAXED,
                               __HIP_MEMORY_SCOPE_AGENT);
    } else {
        if (tid == 0) {
            __hip_atomic_store(&arr[bid * BSTRIDE], phase, __ATOMIC_RELAXED,
                               __HIP_MEMORY_SCOPE_AGENT);
            while (__hip_atomic_load(&rel[bid * BSTRIDE], __ATOMIC_RELAXED,
                                     __HIP_MEMORY_SCOPE_AGENT) < phase)
                __builtin_amdgcn_s_sleep(2);
        }
    }
    __syncthreads();
}

// ---------------------------------------------------------------------------
// prep1: block 0 -> hs_type + hsW1; blocks 1..18 -> ztab rows (self-contained);
// blocks 19+ -> weight swizzle + group_nodes (LDS-aggregated).
// ---------------------------------------------------------------------------
__global__ __launch_bounds__(NTHR) void prep1_kernel(
    const int* __restrict__ gate, const int* __restrict__ lvl,
    const float* __restrict__ Ws, const float* __restrict__ Wt,
    const float* __restrict__ hs_W, const float* __restrict__ hs_b,
    const float* __restrict__ w1, const float* __restrict__ b1,
    const float* __restrict__ w2, const float* __restrict__ b2,
    const float* __restrict__ w3, const float* __restrict__ b3,
    const float* __restrict__ wih,
    float* __restrict__ hs_type, float* __restrict__ hsW1,
    float* __restrict__ ztab,
    unsigned short* __restrict__ wbmlp, unsigned short* __restrict__ wbih,
    int* __restrict__ ncnt, int* __restrict__ nlist, int* __restrict__ nslot) {
    __shared__ float lht[6 * HD];
    __shared__ float s0[HD], s1[HD], s2[HD];
    __shared__ int lcnt[NGROUP], lbase[NGROUP];
    const int bid = blockIdx.x, tid = threadIdx.x;

    if (bid == 0) {
        for (int idx = tid; idx < 6 * HD; idx += NTHR) {
            int t = idx >> 7, c = idx & 127;
            float acc = hs_b[c];
            for (int k = 0; k < HD; k++) acc = fmaf(Ws[t * HD + k], hs_W[k * HD + c], acc);
            for (int k = 0; k < HD; k++) acc = fmaf(Wt[t * HD + k], hs_W[(HD + k) * HD + c], acc);
            lht[idx] = acc;
            hs_type[idx] = acc;
        }
        __syncthreads();
        for (int idx = tid; idx < 3 * 6 * HD; idx += NTHR) {
            int gi = idx / (6 * HD);
            int t = (idx >> 7) % 6;
            int c = idx & 127;
            const float* w = w1 + gi * (2 * HD * HD);  // top half rows 0..127
            float acc = 0.f;
            for (int k = 0; k < HD; k++) acc = fmaf(lht[t * HD + k], w[k * HD + c], acc);
            hsW1[idx] = acc;
        }
    } else if (bid <= 18) {
        // ztab[gi][t] = MLP_gi([hs_type[t], 0]) — fp32, self-contained
        int gi = (bid - 1) / 6, t = (bid - 1) % 6;
        int c = tid;
        if (c < HD) {
            float acc = hs_b[c];
            for (int k = 0; k < HD; k++) acc = fmaf(Ws[t * HD + k], hs_W[k * HD + c], acc);
            for (int k = 0; k < HD; k++) acc = fmaf(Wt[t * HD + k], hs_W[(HD + k) * HD + c], acc);
            s0[c] = acc;
        }
        __syncthreads();
        if (c < HD) {
            const float* w = w1 + gi * (2 * HD * HD);  // top half
            float acc = b1[gi * HD + c];
            for (int k = 0; k < HD; k++) acc = fmaf(s0[k], w[k * HD + c], acc);
            s1[c] = fmaxf(acc, 0.f);
        }
        __syncthreads();
        if (c < HD) {
            const float* w = w2 + gi * (HD * HD);
            float acc = b2[gi * HD + c];
            for (int k = 0; k < HD; k++) acc = fmaf(s1[k], w[k * HD + c], acc);
            s2[c] = fmaxf(acc, 0.f);
        }
        __syncthreads();
        if (c < HD) {
            const float* w = w3 + gi * (HD * HD);
            float acc = b3[gi * HD + c];
            for (int k = 0; k < HD; k++) acc = fmaf(s2[k], w[k * HD + c], acc);
            ztab[(gi * 6 + t) * HD + c] = acc;
        }
    } else {
        const int nb = gridDim.x - 19;          // worker blocks
        const int wb = bid - 19;
        // weight swizzle into MFMA B-fragment layout
        for (int id = wb * NTHR + tid; id < SWTOT; id += nb * NTHR) {
            if (id < 3 * 3 * 16384) {
                int gi = id / 49152;
                int rem = id % 49152;
                int layer = rem / 16384;
                int e = rem % 16384;
                int k = e >> 7, n = e & 127;
                float v;
                if (layer == 0)      v = w1[gi * (2 * HD * HD) + (HD + k) * HD + n];
                else if (layer == 1) v = w2[gi * (HD * HD) + k * HD + n];
                else                 v = w3[gi * (HD * HD) + k * HD + n];
                int nt = n >> 4, kc = k >> 5, kq = (k >> 3) & 3, j = k & 7;
                int L = (kq << 4) | (n & 15);
                wbmlp[(size_t)(gi * 3 + layer) * 16384 + ((nt * 4 + kc) * 64 + L) * 8 + j] = f2bf(v);
            } else {
                int id2 = id - 3 * 3 * 16384;
                int gi = id2 / 49152;
                int e = id2 % 49152;
                int k = e / 384, n = e % 384;             // B[k][n] = wih[n][k]
                float v = wih[gi * (384 * HD) + n * HD + k];
                int nt = n >> 4, kc = k >> 5, kq = (k >> 3) & 3, j = k & 7;
                int L = (kq << 4) | (n & 15);
                wbih[(size_t)gi * 49152 + ((nt * 4 + kc) * 64 + L) * 8 + j] = f2bf(v);
            }
        }
        // group_nodes (LDS-aggregated)
        for (int base = wb * NTHR; base < NN; base += nb * NTHR) {
            if (tid < NGROUP) lcnt[tid] = 0;
            __syncthreads();
            int i = base + tid;
            int glob = -1, local = 0;
            if (i < NN) {
                int gi = gi_of(gate[i]);
                int l = lvl[i];
                if (gi >= 0 && l >= 1) {
                    glob = (l - 1) * 3 + gi;
                    local = atomicAdd(&lcnt[glob], 1);
                }
            }
            __syncthreads();
            if (tid < NGROUP) {
                int cc = lcnt[tid];
                lbase[tid] = cc ? atomicAdd(&ncnt[tid], cc) : 0;
            }
            __syncthreads();
            if (glob >= 0) {
                int slot = lbase[glob] + local;
                if (slot < CAPN) {
                    nlist[glob * CAPN + slot] = i;
                    nslot[i] = slot;
                }
            }
            __syncthreads();
        }
    }
}

// ---------------------------------------------------------------------------
// prep2: hs scatter (hf half is zeroed by hipMemsetAsync) + edge classify.
// Live edges -> per-(group, dst-tile) bucket, packed src|gate|localslot.
// Zero-hf edges -> one int atomicAdd into zcnt[(glob,dslot,src_gate)].
// High-occupancy streaming kernel: 1024 blocks.
// ---------------------------------------------------------------------------
__global__ __launch_bounds__(NTHR) void prep2_kernel(
    const int* __restrict__ gate, const int* __restrict__ lvl,
    const int* __restrict__ ei, const int* __restrict__ nslot,
    const float* __restrict__ hs_type, float* __restrict__ out,
    int* __restrict__ becnt, int* __restrict__ epk,
    int* __restrict__ zcnt) {
    const int stride = gridDim.x * NTHR;
    const int tid0 = blockIdx.x * NTHR + threadIdx.x;

    const float4* ht4 = (const float4*)hs_type;
    float4* o4 = (float4*)out;
    for (int idx = tid0; idx < NN * 32; idx += stride) {
        int i = idx >> 5, q = idx & 31;
        o4[idx] = ht4[gate[i] * 32 + q];
    }

    for (int e = tid0; e < NE; e += stride) {
        int d = ei[NE + e];
        int gd = gi_of(gate[d]);
        int ld = lvl[d];
        if (gd < 0 || ld < 1) continue;
        int g = (ld - 1) * 3 + gd;
        int s = ei[e];
        int dsl = nslot[d];
        int gs = gate[s], ls = lvl[s];
        bool live = (gi_of(gs) >= 0) && (ls >= 1) && (ls < ld);
        if (live) {
            int bucket = g * 64 + (dsl >> 6);
            int slot = atomicAdd(&becnt[bucket], 1);
            if (slot < CAPB)
                epk[(size_t)bucket * CAPB + slot] = s | (gs << 17) | ((dsl & 63) << 23);
        } else {
            atomicAdd(&zcnt[((size_t)g * CAPN + dsl) * 8 + gs], 1);
        }
    }
}

// ---------------------------------------------------------------------------
// levels_kernel: persistent, ONLY the 7 levels + 6 flag-only barriers.
// hf cross-XCD coherence via sc1 (agent-scope) loads/stores -> no L2
// inv/writeback at barriers -> weights/epk/zcnt stay L2-warm across levels.
// Block (gi,tilei) owns dst slots [tile,tile+64) of group gi at every level.
// ---------------------------------------------------------------------------
__global__ __launch_bounds__(NTHR) void levels_kernel(
    const int* ncnt, const int* nlist, const int* becnt, const int* epk,
    const int* zcnt, const float* ztab, const float* hsW1,
    const unsigned short* wbmlp, const unsigned short* wbih,
    const float* b1, const float* b2, const float* b3,
    const float* bih, const float* bhh,
    int* arr, int* rel, float* out) {
    __shared__ unsigned short A[64 * AP];   // 17408 B
    __shared__ float msgf[64 * MP];         // 33792 B
    __shared__ float hsw[6 * 132];          // 3168 B
    __shared__ int zs[64 * 8];              // 2048 B
    __shared__ int nls[7 * 64];             // 1792 B
    __shared__ int ncs[24];
    __shared__ int ecs[8];

    const int gi = blockIdx.x >> 6;
    const int tilei = blockIdx.x & 63;
    const int tile = tilei * 64;
    const int tid = threadIdx.x;
    const int ln = tid & 63, wv = tid >> 6;
    const int lc = ln & 15, quad = ln >> 4;
    const int rbase = wv * 16;

    // ---- prologue: stage all per-block metadata once ----
    if (tid < NGROUP) ncs[tid] = ncnt[tid];
    if (tid >= 32 && tid < 39) ecs[tid - 32] = becnt[((tid - 32) * 3 + gi) * 64 + tilei];
    for (int i = tid; i < 7 * 64; i += NTHR)
        nls[i] = nlist[((i >> 6) * 3 + gi) * CAPN + tile + (i & 63)];
    for (int i = tid; i < 6 * 132; i += NTHR) {
        int t = i / 132, c = i % 132;
        hsw[i] = (c < HD) ? hsW1[(gi * 6 + t) * HD + c] : 0.f;
    }
    for (int i = tid; i < 512; i += NTHR)                       // level-1 zcnt (glob = gi)
        zs[i] = zcnt[((size_t)(gi * CAPN + tile)) * 8 + i];

    float b1v[8], b2v[8], b3v[8];
    float biR[8], bhR[8], biZ[8], bhZ[8], biN[8], bhN[8];
#pragma unroll
    for (int nt = 0; nt < 8; nt++) {
        int c = nt * 16 + lc;
        b1v[nt] = b1[gi * HD + c];
        b2v[nt] = b2[gi * HD + c];
        b3v[nt] = b3[gi * HD + c];
        biR[nt] = bih[gi * 384 + c];        bhR[nt] = bhh[gi * 384 + c];
        biZ[nt] = bih[gi * 384 + 128 + c];  bhZ[nt] = bhh[gi * 384 + 128 + c];
        biN[nt] = bih[gi * 384 + 256 + c];  bhN[nt] = bhh[gi * 384 + 256 + c];
    }
    __syncthreads();

    const f32x4* zt4 = (const f32x4*)ztab;
    const unsigned short* WB = wbmlp + (size_t)gi * 3 * 16384;
    const unsigned short* WG = wbih + (size_t)gi * 49152;
    float* hfbuf = out + (size_t)NN * HD;

    // ---- fold level 1 msg accumulator from staged zcnt ----
    {
        int cnt1 = ncs[gi] > CAPN ? CAPN : ncs[gi];
        if (tile < cnt1) {
            for (int id = tid; id < 64 * 32; id += NTHR) {
                int row = id >> 5, lane = id & 31;
                f32x4 acc = {0.f, 0.f, 0.f, 0.f};
#pragma unroll
                for (int t = 0; t < 6; t++) {
                    int ct = zs[row * 8 + t];
                    if (ct) {
                        float f = (float)ct;
                        f32x4 z = zt4[(gi * 6 + t) * 32 + lane];
                        acc.x = fmaf(f, z.x, acc.x);
                        acc.y = fmaf(f, z.y, acc.y);
                        acc.z = fmaf(f, z.z, acc.z);
                        acc.w = fmaf(f, z.w, acc.w);
                    }
                }
                *(f32x4*)&msgf[row * MP + lane * 4] = acc;
            }
        }
    }
    __syncthreads();

    for (int l = 1; l <= 7; ++l) {
        const int glob = (l - 1) * 3 + gi;
        int cnt0 = ncs[glob]; if (cnt0 > CAPN) cnt0 = CAPN;
        const bool active = (tile < cnt0);
        if (active) {
            const int nv = min(64, cnt0 - tile);
            int ecb = ecs[l - 1]; if (ecb > CAPB) ecb = CAPB;
            if (ecb) {
                const int* ep = epk + (size_t)(glob * 64 + tilei) * CAPB;
                for (int c0 = 0; c0 < ecb; c0 += 64) {
                    int ne = min(64, ecb - c0);
                    // wave-local staging of hf[src] (bf16) via agent-coherent loads
                    {
                        int row = rbase + (ln >> 2), q = ln & 3;
                        unsigned int* Au = (unsigned int*)A;
                        int base = (row * AP + q * 32) >> 1;
                        if (row < ne) {
                            int s = ep[c0 + row] & 0x1FFFF;
                            const unsigned long long* p8 =
                                (const unsigned long long*)(hfbuf + (size_t)s * HD + q * 32);
#pragma unroll
                            for (int i = 0; i < 8; i++) {
                                unsigned long long d0 = coh_load8(p8 + i * 2);
                                unsigned long long d1 = coh_load8(p8 + i * 2 + 1);
                                Au[base + i * 2] =
                                    f2bfu((unsigned int)d0) | (f2bfu((unsigned int)(d0 >> 32)) << 16);
                                Au[base + i * 2 + 1] =
                                    f2bfu((unsigned int)d1) | (f2bfu((unsigned int)(d1 >> 32)) << 16);
                            }
                        } else {
#pragma unroll
                            for (int i = 0; i < 16; i++) Au[base + i] = 0u;
                        }
                    }
                    int sg = 0, lo = 0;
                    if (ln < 16) {
                        int r2 = rbase + ln;
                        if (r2 < ne) {
                            int p = ep[c0 + r2];
                            sg = (p >> 17) & 7;
                            lo = (p >> 23) & 63;
                        }
                    }

                    // layer 1: relu(hsW1[gate_src] + hf@W1bot + b1), in-place
                    {
                        bf16x8 af[4];
#pragma unroll
                        for (int kc = 0; kc < 4; kc++)
                            af[kc] = *(bf16x8*)&A[(rbase + lc) * AP + kc * 32 + quad * 8];
                        for (int nt = 0; nt < 8; nt++) {
                            f32x4 acc = {0.f, 0.f, 0.f, 0.f};
#pragma unroll
                            for (int kc = 0; kc < 4; kc++) {
                                bf16x8 bf = *(const bf16x8*)&WB[((nt * 4 + kc) * 64 + ln) * 8];
                                acc = __builtin_amdgcn_mfma_f32_16x16x32_bf16(af[kc], bf, acc, 0, 0, 0);
                            }
#pragma unroll
                            for (int r = 0; r < 4; r++) {
                                int row = rbase + quad * 4 + r;
                                int sgr = __shfl(sg, quad * 4 + r);
                                float v = acc[r] + hsw[sgr * 132 + nt * 16 + lc] + b1v[nt];
                                A[row * AP + nt * 16 + lc] = f2bf(fmaxf(v, 0.f));
                            }
                        }
                    }
                    // layer 2
                    {
                        bf16x8 af[4];
#pragma unroll
                        for (int kc = 0; kc < 4; kc++)
                            af[kc] = *(bf16x8*)&A[(rbase + lc) * AP + kc * 32 + quad * 8];
                        for (int nt = 0; nt < 8; nt++) {
                            f32x4 acc = {0.f, 0.f, 0.f, 0.f};
#pragma unroll
                            for (int kc = 0; kc < 4; kc++) {
                                bf16x8 bf = *(const bf16x8*)&WB[16384 + ((nt * 4 + kc) * 64 + ln) * 8];
                                acc = __builtin_amdgcn_mfma_f32_16x16x32_bf16(af[kc], bf, acc, 0, 0, 0);
                            }
#pragma unroll
                            for (int r = 0; r < 4; r++) {
                                int row = rbase + quad * 4 + r;
                                A[row * AP + nt * 16 + lc] = f2bf(fmaxf(acc[r] + b2v[nt], 0.f));
                            }
                        }
                    }
                    // layer 3 + LDS scatter-add into msgf
                    {
                        bf16x8 af[4];
#pragma unroll
                        for (int kc = 0; kc < 4; kc++)
                            af[kc] = *(bf16x8*)&A[(rbase + lc) * AP + kc * 32 + quad * 8];
                        for (int nt = 0; nt < 8; nt++) {
                            f32x4 acc = {0.f, 0.f, 0.f, 0.f};
#pragma unroll
                            for (int kc = 0; kc < 4; kc++) {
                                bf16x8 bf = *(const bf16x8*)&WB[2 * 16384 + ((nt * 4 + kc) * 64 + ln) * 8];
                                acc = __builtin_amdgcn_mfma_f32_16x16x32_bf16(af[kc], bf, acc, 0, 0, 0);
                            }
#pragma unroll
                            for (int r = 0; r < 4; r++) {
                                int row = rbase + quad * 4 + r;
                                if (row < ne) {
                                    int lr = __shfl(lo, quad * 4 + r);
                                    atomicAdd(&msgf[lr * MP + nt * 16 + lc], acc[r] + b3v[nt]);
                                }
                            }
                        }
                    }
                }
            }
            __syncthreads();   // edge atomics visible before GRU reads msgf

            // ---- GRU: gin = msg @ wih.T + bih ; gh = bhh (h_old == 0) ----
            int nd = -1;
            if (ln < 16) {
                int r2 = rbase + ln;
                nd = (r2 < nv) ? nls[(l - 1) * 64 + r2] : -1;
            }
            bf16x8 af[4];
#pragma unroll
            for (int kc = 0; kc < 4; kc++) {
                const float* mp = &msgf[(rbase + lc) * MP + kc * 32 + quad * 8];
                f32x4 v0 = *(const f32x4*)mp;
                f32x4 v1 = *(const f32x4*)(mp + 4);
                bf16x8 a;
                a[0] = (short)f2bf(v0.x); a[1] = (short)f2bf(v0.y);
                a[2] = (short)f2bf(v0.z); a[3] = (short)f2bf(v0.w);
                a[4] = (short)f2bf(v1.x); a[5] = (short)f2bf(v1.y);
                a[6] = (short)f2bf(v1.z); a[7] = (short)f2bf(v1.w);
                af[kc] = a;
            }
            for (int nt = 0; nt < 8; nt++) {
                f32x4 aR = {0.f, 0.f, 0.f, 0.f};
                f32x4 aZ = {0.f, 0.f, 0.f, 0.f};
                f32x4 aN = {0.f, 0.f, 0.f, 0.f};
#pragma unroll
                for (int kc = 0; kc < 4; kc++) {
                    bf16x8 bR = *(const bf16x8*)&WG[(((nt)      * 4 + kc) * 64 + ln) * 8];
                    bf16x8 bZ = *(const bf16x8*)&WG[(((nt + 8)  * 4 + kc) * 64 + ln) * 8];
                    bf16x8 bN = *(const bf16x8*)&WG[(((nt + 16) * 4 + kc) * 64 + ln) * 8];
                    aR = __builtin_amdgcn_mfma_f32_16x16x32_bf16(af[kc], bR, aR, 0, 0, 0);
                    aZ = __builtin_amdgcn_mfma_f32_16x16x32_bf16(af[kc], bZ, aZ, 0, 0, 0);
                    aN = __builtin_amdgcn_mfma_f32_16x16x32_bf16(af[kc], bN, aN, 0, 0, 0);
                }
                int c = nt * 16 + lc;
#pragma unroll
                for (int r = 0; r < 4; r++) {
                    int row = rbase + quad * 4 + r;
                    int n = __shfl(nd, quad * 4 + r);
                    if (n >= 0 && row < nv) {
                        float ir = aR[r] + biR[nt] + bhR[nt];
                        float iz = aZ[r] + biZ[nt] + bhZ[nt];
                        float inn = aN[r] + biN[nt];
                        float rg = 1.f / (1.f + expf(-ir));
                        float zg = 1.f / (1.f + expf(-iz));
                        float nst = tanhf(inn + rg * bhN[nt]);
                        // agent-coherent write-through: visible to all XCDs
                        // after the next barrier without any L2 flush/inv
                        coh_store4(&hfbuf[(size_t)n * HD + c], (1.f - zg) * nst);
                    }
                }
            }
        }

        if (l < 7) {
            __syncthreads();                 // all waves done reading msgf / zs
            // fold msg accumulator for level l+1 (independent of hf)
            const int globn = l * 3 + gi;
            for (int i = tid; i < 512; i += NTHR)
                zs[i] = zcnt[((size_t)(globn * CAPN + tile)) * 8 + i];
            __syncthreads();
            int cntn = ncs[globn]; if (cntn > CAPN) cntn = CAPN;
            if (tile < cntn) {
                for (int id = tid; id < 64 * 32; id += NTHR) {
                    int row = id >> 5, lane = id & 31;
                    f32x4 acc = {0.f, 0.f, 0.f, 0.f};
#pragma unroll
                    for (int t = 0; t < 6; t++) {
                        int ct = zs[row * 8 + t];
                        if (ct) {
                            float f = (float)ct;
                            f32x4 z = zt4[(gi * 6 + t) * 32 + lane];
                            acc.x = fmaf(f, z.x, acc.x);
                            acc.y = fmaf(f, z.y, acc.y);
                            acc.z = fmaf(f, z.z, acc.z);
                            acc.w = fmaf(f, z.w, acc.w);
                        }
                    }
                    *(f32x4*)&msgf[row * MP + lane * 4] = acc;
                }
            }
            grid_barrier(arr, rel, l);       // flag-only; hf already written through
        }
    }
}

extern "C" void kernel_launch(void* const* d_in, const int* in_sizes, int n_in,
                              void* d_out, int out_size, void* d_ws, size_t ws_size,
                              hipStream_t stream) {
    const int* gate = (const int*)d_in[0];
    const int* lvl  = (const int*)d_in[1];
    const int* ei   = (const int*)d_in[2];
    const float* Ws   = (const float*)d_in[3];
    const float* Wt   = (const float*)d_in[4];
    const float* hs_W = (const float*)d_in[5];
    const float* hs_b = (const float*)d_in[6];
    const float* w1 = (const float*)d_in[7];
    const float* b1 = (const float*)d_in[8];
    const float* w2 = (const float*)d_in[9];
    const float* b2 = (const float*)d_in[10];
    const float* w3 = (const float*)d_in[11];
    const float* b3 = (const float*)d_in[12];
    const float* wih = (const float*)d_in[13];
    // d_in[14] = gru_whh: unused (h_old provably zero for every updated node)
    const float* bih = (const float*)d_in[15];
    const float* bhh = (const float*)d_in[16];
    float* out = (float*)d_out;
    char* ws = (char*)d_ws;

    int*   ncnt    = (int*)(ws + OFF_NCNT);
    int*   arr     = (int*)(ws + OFF_ARR);
    int*   rel     = (int*)(ws + OFF_REL);
    int*   becnt   = (int*)(ws + OFF_BECNT);
    int*   zcnt    = (int*)(ws + OFF_ZCNT);
    float* hs_type = (float*)(ws + OFF_HSTYPE);
    float* hsW1    = (float*)(ws + OFF_HSW1);
    float* ztab    = (float*)(ws + OFF_ZTAB);
    unsigned short* wbmlp = (unsigned short*)(ws + OFF_WBMLP);
    unsigned short* wbih  = (unsigned short*)(ws + OFF_WBIH);
    int*   nlist   = (int*)(ws + OFF_NLIST);
    int*   nslot   = (int*)(ws + OFF_NSLOT);
    int*   epk     = (int*)(ws + OFF_EPK);

    hipMemsetAsync(ws, 0, MEMSET_BYTES, stream);
    // hf half of the output: zero via fill engine
    hipMemsetAsync(out + (size_t)NN * HD, 0, (size_t)NN * HD * sizeof(float), stream);

    prep1_kernel<<<256, NTHR, 0, stream>>>(gate, lvl, Ws, Wt, hs_W, hs_b,
                                           w1, b1, w2, b2, w3, b3, wih,
                                           hs_type, hsW1, ztab, wbmlp, wbih,
                                           ncnt, nlist, nslot);
    prep2_kernel<<<1024, NTHR, 0, stream>>>(gate, lvl, ei, nslot, hs_type, out,
                                            becnt, epk, zcnt);

    levels_kernel<<<NBLK, NTHR, 0, stream>>>(ncnt, nlist, becnt, epk, zcnt,
                                             ztab, hsW1, wbmlp, wbih,
                                             b1, b2, b3, bih, bhh,
                                             arr, rel, out);
}

// Round 7
// 456.316 us; speedup vs baseline: 1.9056x; 1.0507x over previous
//
#include <hip/hip_runtime.h>
#include <math.h>

#define NN 100000
#define NE 200000
#define HD 128
#define CAPN 4096
#define CAPB 256
#define NGROUP 21
#define AP 136   // bf16 LDS row pitch (shorts)
#define MP 132   // f32 LDS msg row pitch
#define NTHR 256

typedef short bf16x8 __attribute__((ext_vector_type(8)));
typedef float f32x4 __attribute__((ext_vector_type(4)));

// workspace byte offsets
#define OFF_NCNT   0                // 21 ints (pad to 128)
#define OFF_BECNT  128              // 1344 ints (live edges per (group,dst-tile) bucket)
#define OFF_ZCNT   5504             // 21*4096*8 ints (zero-edge counts per dst,src-gate)
#define MEMSET_BYTES 2758016        // covers ncnt+becnt+zcnt
#define OFF_HSTYPE 2758016          // 6*128 f32
#define OFF_HSW1   2761088          // 3*6*128 f32
#define OFF_ZTAB   2770304          // 3*6*128 f32 (msg of a zero-hf src, per gi,src-gate)
#define OFF_WBMLP  2779520          // 3*3*16384 bf16 swizzled B-frags
#define OFF_WBIH   3074432          // 3*49152 bf16 swizzled B-frags
#define OFF_NLIST  3369344          // 21*4096 ints
#define OFF_NSLOT  3713408          // NN ints
#define OFF_EPK    4113408          // 1344*256 ints: src | gate<<17 | localslot<<23
#define OFF_MSG    5489664          // 21*4096*128 f32 (dense tiles, written by msg_kernel)

#define SWTOT (3 * 3 * 16384 + 3 * 49152)

__device__ __forceinline__ int gi_of(int g) {
    return (g == 3) ? 0 : (g == 2) ? 1 : (g == 5) ? 2 : -1;
}

__device__ __forceinline__ unsigned short f2bf(float f) {
    unsigned int u = __float_as_uint(f);
    u += 0x7FFF + ((u >> 16) & 1);   // RNE
    return (unsigned short)(u >> 16);
}

// ---------------------------------------------------------------------------
// prep1: block 0 -> hs_type + hsW1; blocks 1..18 -> ztab rows (self-contained);
// blocks 19+ -> weight swizzle + group_nodes (LDS-aggregated).
// ---------------------------------------------------------------------------
__global__ __launch_bounds__(NTHR) void prep1_kernel(
    const int* __restrict__ gate, const int* __restrict__ lvl,
    const float* __restrict__ Ws, const float* __restrict__ Wt,
    const float* __restrict__ hs_W, const float* __restrict__ hs_b,
    const float* __restrict__ w1, const float* __restrict__ b1,
    const float* __restrict__ w2, const float* __restrict__ b2,
    const float* __restrict__ w3, const float* __restrict__ b3,
    const float* __restrict__ wih,
    float* __restrict__ hs_type, float* __restrict__ hsW1,
    float* __restrict__ ztab,
    unsigned short* __restrict__ wbmlp, unsigned short* __restrict__ wbih,
    int* __restrict__ ncnt, int* __restrict__ nlist, int* __restrict__ nslot) {
    __shared__ float lht[6 * HD];
    __shared__ float s0[HD], s1[HD], s2[HD];
    __shared__ int lcnt[NGROUP], lbase[NGROUP];
    const int bid = blockIdx.x, tid = threadIdx.x;

    if (bid == 0) {
        for (int idx = tid; idx < 6 * HD; idx += NTHR) {
            int t = idx >> 7, c = idx & 127;
            float acc = hs_b[c];
            for (int k = 0; k < HD; k++) acc = fmaf(Ws[t * HD + k], hs_W[k * HD + c], acc);
            for (int k = 0; k < HD; k++) acc = fmaf(Wt[t * HD + k], hs_W[(HD + k) * HD + c], acc);
            lht[idx] = acc;
            hs_type[idx] = acc;
        }
        __syncthreads();
        for (int idx = tid; idx < 3 * 6 * HD; idx += NTHR) {
            int gi = idx / (6 * HD);
            int t = (idx >> 7) % 6;
            int c = idx & 127;
            const float* w = w1 + gi * (2 * HD * HD);  // top half rows 0..127
            float acc = 0.f;
            for (int k = 0; k < HD; k++) acc = fmaf(lht[t * HD + k], w[k * HD + c], acc);
            hsW1[idx] = acc;
        }
    } else if (bid <= 18) {
        // ztab[gi][t] = MLP_gi([hs_type[t], 0]) — fp32, self-contained
        int gi = (bid - 1) / 6, t = (bid - 1) % 6;
        int c = tid;
        if (c < HD) {
            float acc = hs_b[c];
            for (int k = 0; k < HD; k++) acc = fmaf(Ws[t * HD + k], hs_W[k * HD + c], acc);
            for (int k = 0; k < HD; k++) acc = fmaf(Wt[t * HD + k], hs_W[(HD + k) * HD + c], acc);
            s0[c] = acc;
        }
        __syncthreads();
        if (c < HD) {
            const float* w = w1 + gi * (2 * HD * HD);  // top half
            float acc = b1[gi * HD + c];
            for (int k = 0; k < HD; k++) acc = fmaf(s0[k], w[k * HD + c], acc);
            s1[c] = fmaxf(acc, 0.f);
        }
        __syncthreads();
        if (c < HD) {
            const float* w = w2 + gi * (HD * HD);
            float acc = b2[gi * HD + c];
            for (int k = 0; k < HD; k++) acc = fmaf(s1[k], w[k * HD + c], acc);
            s2[c] = fmaxf(acc, 0.f);
        }
        __syncthreads();
        if (c < HD) {
            const float* w = w3 + gi * (HD * HD);
            float acc = b3[gi * HD + c];
            for (int k = 0; k < HD; k++) acc = fmaf(s2[k], w[k * HD + c], acc);
            ztab[(gi * 6 + t) * HD + c] = acc;
        }
    } else {
        const int nb = gridDim.x - 19;          // worker blocks
        const int wb = bid - 19;
        // weight swizzle into MFMA B-fragment layout
        for (int id = wb * NTHR + tid; id < SWTOT; id += nb * NTHR) {
            if (id < 3 * 3 * 16384) {
                int gi = id / 49152;
                int rem = id % 49152;
                int layer = rem / 16384;
                int e = rem % 16384;
                int k = e >> 7, n = e & 127;
                float v;
                if (layer == 0)      v = w1[gi * (2 * HD * HD) + (HD + k) * HD + n];
                else if (layer == 1) v = w2[gi * (HD * HD) + k * HD + n];
                else                 v = w3[gi * (HD * HD) + k * HD + n];
                int nt = n >> 4, kc = k >> 5, kq = (k >> 3) & 3, j = k & 7;
                int L = (kq << 4) | (n & 15);
                wbmlp[(size_t)(gi * 3 + layer) * 16384 + ((nt * 4 + kc) * 64 + L) * 8 + j] = f2bf(v);
            } else {
                int id2 = id - 3 * 3 * 16384;
                int gi = id2 / 49152;
                int e = id2 % 49152;
                int k = e / 384, n = e % 384;             // B[k][n] = wih[n][k]
                float v = wih[gi * (384 * HD) + n * HD + k];
                int nt = n >> 4, kc = k >> 5, kq = (k >> 3) & 3, j = k & 7;
                int L = (kq << 4) | (n & 15);
                wbih[(size_t)gi * 49152 + ((nt * 4 + kc) * 64 + L) * 8 + j] = f2bf(v);
            }
        }
        // group_nodes (LDS-aggregated)
        for (int base = wb * NTHR; base < NN; base += nb * NTHR) {
            if (tid < NGROUP) lcnt[tid] = 0;
            __syncthreads();
            int i = base + tid;
            int glob = -1, local = 0;
            if (i < NN) {
                int gi = gi_of(gate[i]);
                int l = lvl[i];
                if (gi >= 0 && l >= 1) {
                    glob = (l - 1) * 3 + gi;
                    local = atomicAdd(&lcnt[glob], 1);
                }
            }
            __syncthreads();
            if (tid < NGROUP) {
                int cc = lcnt[tid];
                lbase[tid] = cc ? atomicAdd(&ncnt[tid], cc) : 0;
            }
            __syncthreads();
            if (glob >= 0) {
                int slot = lbase[glob] + local;
                if (slot < CAPN) {
                    nlist[glob * CAPN + slot] = i;
                    nslot[i] = slot;
                }
            }
            __syncthreads();
        }
    }
}

// ---------------------------------------------------------------------------
// prep2: hs scatter (hf half zeroed by hipMemsetAsync) + edge classify.
// Live edges -> per-(group, dst-tile) bucket, packed src|gate|localslot.
// Zero-hf edges -> one int atomicAdd into zcnt[(glob,dslot,src_gate)].
// ---------------------------------------------------------------------------
__global__ __launch_bounds__(NTHR) void prep2_kernel(
    const int* __restrict__ gate, const int* __restrict__ lvl,
    const int* __restrict__ ei, const int* __restrict__ nslot,
    const float* __restrict__ hs_type, float* __restrict__ out,
    int* __restrict__ becnt, int* __restrict__ epk,
    int* __restrict__ zcnt) {
    const int stride = gridDim.x * NTHR;
    const int tid0 = blockIdx.x * NTHR + threadIdx.x;

    const float4* ht4 = (const float4*)hs_type;
    float4* o4 = (float4*)out;
    for (int idx = tid0; idx < NN * 32; idx += stride) {
        int i = idx >> 5, q = idx & 31;
        o4[idx] = ht4[gate[i] * 32 + q];
    }

    for (int e = tid0; e < NE; e += stride) {
        int d = ei[NE + e];
        int gd = gi_of(gate[d]);
        int ld = lvl[d];
        if (gd < 0 || ld < 1) continue;
        int g = (ld - 1) * 3 + gd;
        int s = ei[e];
        int dsl = nslot[d];
        int gs = gate[s], ls = lvl[s];
        bool live = (gi_of(gs) >= 0) && (ls >= 1) && (ls < ld);
        if (live) {
            int bucket = g * 64 + (dsl >> 6);
            int slot = atomicAdd(&becnt[bucket], 1);
            if (slot < CAPB)
                epk[(size_t)bucket * CAPB + slot] = s | (gs << 17) | ((dsl & 63) << 23);
        } else {
            atomicAdd(&zcnt[((size_t)g * CAPN + dsl) * 8 + gs], 1);
        }
    }
}

// ---------------------------------------------------------------------------
// msg_kernel: live-edge 3-layer MFMA MLP for one (group, dst-tile) bucket.
// One block owns ALL live edges of its tile -> LDS accumulation only, then a
// single dense non-atomic 32KB tile write. No global msg zero-init needed.
// grid = 3 x 64. Kernel-boundary coherence covers hf reads (prior gru).
// ---------------------------------------------------------------------------
__global__ __launch_bounds__(NTHR) void msg_kernel(
    int level, const float* __restrict__ hf,
    const unsigned short* __restrict__ wbmlp,
    const float* __restrict__ b1, const float* __restrict__ b2,
    const float* __restrict__ b3, const float* __restrict__ hsW1,
    const int* __restrict__ becnt, const int* __restrict__ epk,
    float* __restrict__ msg) {
    __shared__ unsigned short A[64 * AP];   // 17408 B
    __shared__ float msgf[64 * MP];         // 33792 B
    __shared__ float hsw[6 * 132];          // 3168 B

    const int gi = blockIdx.x >> 6;
    const int tilei = blockIdx.x & 63;
    const int glob = (level - 1) * 3 + gi;
    const int bucket = glob * 64 + tilei;
    int ecb = becnt[bucket]; if (ecb > CAPB) ecb = CAPB;
    if (ecb == 0) return;

    const int tid = threadIdx.x;
    const int ln = tid & 63, wv = tid >> 6;
    const int lc = ln & 15, quad = ln >> 4;
    const int rbase = wv * 16;

    for (int i = tid; i < 6 * 132; i += NTHR) {
        int t = i / 132, c = i % 132;
        hsw[i] = (c < HD) ? hsW1[(gi * 6 + t) * HD + c] : 0.f;
    }
    for (int id = tid; id < 64 * 32; id += NTHR)
        *(f32x4*)&msgf[(id >> 5) * MP + (id & 31) * 4] = f32x4{0.f, 0.f, 0.f, 0.f};

    const unsigned short* WB = wbmlp + (size_t)gi * 3 * 16384;
    float b1v[8], b2v[8], b3v[8];
#pragma unroll
    for (int nt = 0; nt < 8; nt++) {
        b1v[nt] = b1[gi * HD + nt * 16 + lc];
        b2v[nt] = b2[gi * HD + nt * 16 + lc];
        b3v[nt] = b3[gi * HD + nt * 16 + lc];
    }
    __syncthreads();

    const int* ep = epk + (size_t)bucket * CAPB;
    for (int c0 = 0; c0 < ecb; c0 += 64) {
        int ne = min(64, ecb - c0);
        // wave-local staging of hf[src] (bf16)
        {
            int row = rbase + (ln >> 2), q = ln & 3;
            unsigned int* Au = (unsigned int*)A;
            int base = (row * AP + q * 32) >> 1;
            if (row < ne) {
                int s = ep[c0 + row] & 0x1FFFF;
                const float4* src4 = (const float4*)(hf + (size_t)s * HD + q * 32);
#pragma unroll
                for (int i = 0; i < 8; i++) {
                    float4 v = src4[i];
                    Au[base + i * 2]     = f2bf(v.x) | ((unsigned int)f2bf(v.y) << 16);
                    Au[base + i * 2 + 1] = f2bf(v.z) | ((unsigned int)f2bf(v.w) << 16);
                }
            } else {
#pragma unroll
                for (int i = 0; i < 16; i++) Au[base + i] = 0u;
            }
        }
        int sg = 0, lo = 0;
        if (ln < 16) {
            int r2 = rbase + ln;
            if (r2 < ne) {
                int p = ep[c0 + r2];
                sg = (p >> 17) & 7;
                lo = (p >> 23) & 63;
            }
        }

        // layer 1: relu(hsW1[gate_src] + hf@W1bot + b1), in-place
        {
            bf16x8 af[4];
#pragma unroll
            for (int kc = 0; kc < 4; kc++)
                af[kc] = *(bf16x8*)&A[(rbase + lc) * AP + kc * 32 + quad * 8];
            for (int nt = 0; nt < 8; nt++) {
                f32x4 acc = {0.f, 0.f, 0.f, 0.f};
#pragma unroll
                for (int kc = 0; kc < 4; kc++) {
                    bf16x8 bf = *(const bf16x8*)&WB[((nt * 4 + kc) * 64 + ln) * 8];
                    acc = __builtin_amdgcn_mfma_f32_16x16x32_bf16(af[kc], bf, acc, 0, 0, 0);
                }
#pragma unroll
                for (int r = 0; r < 4; r++) {
                    int row = rbase + quad * 4 + r;
                    int sgr = __shfl(sg, quad * 4 + r);
                    float v = acc[r] + hsw[sgr * 132 + nt * 16 + lc] + b1v[nt];
                    A[row * AP + nt * 16 + lc] = f2bf(fmaxf(v, 0.f));
                }
            }
        }
        // layer 2
        {
            bf16x8 af[4];
#pragma unroll
            for (int kc = 0; kc < 4; kc++)
                af[kc] = *(bf16x8*)&A[(rbase + lc) * AP + kc * 32 + quad * 8];
            for (int nt = 0; nt < 8; nt++) {
                f32x4 acc = {0.f, 0.f, 0.f, 0.f};
#pragma unroll
                for (int kc = 0; kc < 4; kc++) {
                    bf16x8 bf = *(const bf16x8*)&WB[16384 + ((nt * 4 + kc) * 64 + ln) * 8];
                    acc = __builtin_amdgcn_mfma_f32_16x16x32_bf16(af[kc], bf, acc, 0, 0, 0);
                }
#pragma unroll
                for (int r = 0; r < 4; r++) {
                    int row = rbase + quad * 4 + r;
                    A[row * AP + nt * 16 + lc] = f2bf(fmaxf(acc[r] + b2v[nt], 0.f));
                }
            }
        }
        // layer 3 + LDS scatter-add into msgf
        {
            bf16x8 af[4];
#pragma unroll
            for (int kc = 0; kc < 4; kc++)
                af[kc] = *(bf16x8*)&A[(rbase + lc) * AP + kc * 32 + quad * 8];
            for (int nt = 0; nt < 8; nt++) {
                f32x4 acc = {0.f, 0.f, 0.f, 0.f};
#pragma unroll
                for (int kc = 0; kc < 4; kc++) {
                    bf16x8 bf = *(const bf16x8*)&WB[2 * 16384 + ((nt * 4 + kc) * 64 + ln) * 8];
                    acc = __builtin_amdgcn_mfma_f32_16x16x32_bf16(af[kc], bf, acc, 0, 0, 0);
                }
#pragma unroll
                for (int r = 0; r < 4; r++) {
                    int row = rbase + quad * 4 + r;
                    if (row < ne) {
                        int lr = __shfl(lo, quad * 4 + r);
                        atomicAdd(&msgf[lr * MP + nt * 16 + lc], acc[r] + b3v[nt]);
                    }
                }
            }
        }
    }
    __syncthreads();

    // dense non-atomic tile write (rows beyond node count are 0; gru ignores)
    float* msgL = msg + ((size_t)glob * CAPN + tilei * 64) * HD;
    for (int id = tid; id < 64 * 32; id += NTHR) {
        int row = id >> 5, lane = id & 31;
        *(f32x4*)&msgL[(size_t)row * HD + lane * 4] = *(const f32x4*)&msgf[row * MP + lane * 4];
    }
}

// ---------------------------------------------------------------------------
// gru_kernel: msgf = zcnt-fold (ztab) + msg tile (if bucket nonempty), then
// gin = msgf @ wih.T + bih ; gh = bhh (h_old == 0). prep3 is gone — the fold
// happens here. grid = 3 x 64.
// ---------------------------------------------------------------------------
__global__ __launch_bounds__(NTHR) void gru_kernel(
    int level, const int* __restrict__ ncnt, const int* __restrict__ nlist,
    const int* __restrict__ becnt, const int* __restrict__ zcnt,
    const float* __restrict__ ztab, const unsigned short* __restrict__ wbih,
    const float* __restrict__ bih, const float* __restrict__ bhh,
    const float* __restrict__ msg, float* __restrict__ out) {
    __shared__ float msgf[64 * MP];         // 33792 B
    __shared__ int zs[64 * 8];              // 2048 B

    const int gi = blockIdx.x >> 6;
    const int tilei = blockIdx.x & 63;
    const int glob = (level - 1) * 3 + gi;
    int cnt = ncnt[glob]; if (cnt > CAPN) cnt = CAPN;
    const int tile = tilei * 64;
    if (tile >= cnt) return;
    const int nv = min(64, cnt - tile);

    const int tid = threadIdx.x;
    const int ln = tid & 63, wv = tid >> 6;
    const int lc = ln & 15, quad = ln >> 4;
    const int rbase = wv * 16;

    for (int i = tid; i < 512; i += NTHR)
        zs[i] = zcnt[((size_t)(glob * CAPN + tile)) * 8 + i];
    __syncthreads();

    const int ecb = becnt[glob * 64 + tilei];
    const f32x4* zt4 = (const f32x4*)ztab;
    const f32x4* mt4 = (const f32x4*)(msg + ((size_t)glob * CAPN + tile) * HD);
    for (int id = tid; id < 64 * 32; id += NTHR) {
        int row = id >> 5, lane = id & 31;
        f32x4 acc = ecb ? mt4[row * 32 + lane] : f32x4{0.f, 0.f, 0.f, 0.f};
#pragma unroll
        for (int t = 0; t < 6; t++) {
            int ct = zs[row * 8 + t];
            if (ct) {
                float f = (float)ct;
                f32x4 z = zt4[(gi * 6 + t) * 32 + lane];
                acc.x = fmaf(f, z.x, acc.x);
                acc.y = fmaf(f, z.y, acc.y);
                acc.z = fmaf(f, z.z, acc.z);
                acc.w = fmaf(f, z.w, acc.w);
            }
        }
        *(f32x4*)&msgf[row * MP + lane * 4] = acc;
    }
    __syncthreads();

    int nd = -1;
    if (ln < 16) {
        int r2 = rbase + ln;
        nd = (r2 < nv) ? nlist[glob * CAPN + tile + r2] : -1;
    }
    bf16x8 af[4];
#pragma unroll
    for (int kc = 0; kc < 4; kc++) {
        const float* mp = &msgf[(rbase + lc) * MP + kc * 32 + quad * 8];
        f32x4 v0 = *(const f32x4*)mp;
        f32x4 v1 = *(const f32x4*)(mp + 4);
        bf16x8 a;
        a[0] = (short)f2bf(v0.x); a[1] = (short)f2bf(v0.y);
        a[2] = (short)f2bf(v0.z); a[3] = (short)f2bf(v0.w);
        a[4] = (short)f2bf(v1.x); a[5] = (short)f2bf(v1.y);
        a[6] = (short)f2bf(v1.z); a[7] = (short)f2bf(v1.w);
        af[kc] = a;
    }

    const unsigned short* WG = wbih + (size_t)gi * 49152;
    float* hfout = out + (size_t)NN * HD;
    for (int nt = 0; nt < 8; nt++) {
        f32x4 aR = {0.f, 0.f, 0.f, 0.f};
        f32x4 aZ = {0.f, 0.f, 0.f, 0.f};
        f32x4 aN = {0.f, 0.f, 0.f, 0.f};
#pragma unroll
        for (int kc = 0; kc < 4; kc++) {
            bf16x8 bR = *(const bf16x8*)&WG[(((nt)      * 4 + kc) * 64 + ln) * 8];
            bf16x8 bZ = *(const bf16x8*)&WG[(((nt + 8)  * 4 + kc) * 64 + ln) * 8];
            bf16x8 bN = *(const bf16x8*)&WG[(((nt + 16) * 4 + kc) * 64 + ln) * 8];
            aR = __builtin_amdgcn_mfma_f32_16x16x32_bf16(af[kc], bR, aR, 0, 0, 0);
            aZ = __builtin_amdgcn_mfma_f32_16x16x32_bf16(af[kc], bZ, aZ, 0, 0, 0);
            aN = __builtin_amdgcn_mfma_f32_16x16x32_bf16(af[kc], bN, aN, 0, 0, 0);
        }
        int c = nt * 16 + lc;
        float biR = bih[gi * 384 + c],       bhR = bhh[gi * 384 + c];
        float biZ = bih[gi * 384 + 128 + c], bhZ = bhh[gi * 384 + 128 + c];
        float biN = bih[gi * 384 + 256 + c], bhN = bhh[gi * 384 + 256 + c];
#pragma unroll
        for (int r = 0; r < 4; r++) {
            int row = rbase + quad * 4 + r;
            int n = __shfl(nd, quad * 4 + r);
            if (n >= 0 && row < nv) {
                float ir = aR[r] + biR + bhR;
                float iz = aZ[r] + biZ + bhZ;
                float inn = aN[r] + biN;
                float rg = 1.f / (1.f + expf(-ir));
                float zg = 1.f / (1.f + expf(-iz));
                float nst = tanhf(inn + rg * bhN);
                hfout[(size_t)n * HD + c] = (1.f - zg) * nst;
            }
        }
    }
}

extern "C" void kernel_launch(void* const* d_in, const int* in_sizes, int n_in,
                              void* d_out, int out_size, void* d_ws, size_t ws_size,
                              hipStream_t stream) {
    const int* gate = (const int*)d_in[0];
    const int* lvl  = (const int*)d_in[1];
    const int* ei   = (const int*)d_in[2];
    const float* Ws   = (const float*)d_in[3];
    const float* Wt   = (const float*)d_in[4];
    const float* hs_W = (const float*)d_in[5];
    const float* hs_b = (const float*)d_in[6];
    const float* w1 = (const float*)d_in[7];
    const float* b1 = (const float*)d_in[8];
    const float* w2 = (const float*)d_in[9];
    const float* b2 = (const float*)d_in[10];
    const float* w3 = (const float*)d_in[11];
    const float* b3 = (const float*)d_in[12];
    const float* wih = (const float*)d_in[13];
    // d_in[14] = gru_whh: unused (h_old provably zero for every updated node)
    const float* bih = (const float*)d_in[15];
    const float* bhh = (const float*)d_in[16];
    float* out = (float*)d_out;
    char* ws = (char*)d_ws;

    int*   ncnt    = (int*)(ws + OFF_NCNT);
    int*   becnt   = (int*)(ws + OFF_BECNT);
    int*   zcnt    = (int*)(ws + OFF_ZCNT);
    float* hs_type = (float*)(ws + OFF_HSTYPE);
    float* hsW1    = (float*)(ws + OFF_HSW1);
    float* ztab    = (float*)(ws + OFF_ZTAB);
    unsigned short* wbmlp = (unsigned short*)(ws + OFF_WBMLP);
    unsigned short* wbih  = (unsigned short*)(ws + OFF_WBIH);
    int*   nlist   = (int*)(ws + OFF_NLIST);
    int*   nslot   = (int*)(ws + OFF_NSLOT);
    int*   epk     = (int*)(ws + OFF_EPK);
    float* msg     = (float*)(ws + OFF_MSG);

    hipMemsetAsync(ws, 0, MEMSET_BYTES, stream);
    // hf half of the output: zero via fill engine
    hipMemsetAsync(out + (size_t)NN * HD, 0, (size_t)NN * HD * sizeof(float), stream);

    prep1_kernel<<<256, NTHR, 0, stream>>>(gate, lvl, Ws, Wt, hs_W, hs_b,
                                           w1, b1, w2, b2, w3, b3, wih,
                                           hs_type, hsW1, ztab, wbmlp, wbih,
                                           ncnt, nlist, nslot);
    prep2_kernel<<<1024, NTHR, 0, stream>>>(gate, lvl, ei, nslot, hs_type, out,
                                            becnt, epk, zcnt);

    const float* hf = out + (size_t)NN * HD;
    for (int l = 1; l < 8; l++) {
        if (l > 1)  // level 1 provably has zero live edges
            msg_kernel<<<3 * 64, NTHR, 0, stream>>>(l, hf, wbmlp, b1, b2, b3,
                                                    hsW1, becnt, epk, msg);
        gru_kernel<<<3 * 64, NTHR, 0, stream>>>(l, ncnt, nlist, becnt, zcnt,
                                                ztab, wbih, bih, bhh, msg, out);
    }
}